// Round 1
// baseline (1171.546 us; speedup 1.0000x reference)
//
#include <hip/hip_runtime.h>
#include <hip/hip_bf16.h>
#include <cstdint>
#include <cstddef>

// Problem constants
#define B_   2
#define T_   4096
#define E_   1024
#define H_   16
#define D_   64
#define M_   (B_ * T_)       // 8192 rows
#define KDIM 1024
#define NDIM 1024
#define EPSC 1e-6f
#define CT   128             // chunk length for the recurrence
#define NC   (T_ / CT)       // 32 chunks per (b,h)

// ---------- small helpers ----------
__device__ __forceinline__ float bf2f(uint32_t u) {
    union { uint32_t u; float f; } x; x.u = u << 16; return x.f;
}
__device__ __forceinline__ unsigned short f2bf(float f) {
    union { float f; uint32_t u; } x; x.f = f;
    uint32_t r = x.u + 0x7fffu + ((x.u >> 16) & 1u);   // round-to-nearest-even
    return (unsigned short)(r >> 16);
}
__device__ __forceinline__ void decode4(uint2 r, float* dst) {
    dst[0] = bf2f(r.x & 0xffffu);
    dst[1] = bf2f(r.x >> 16);
    dst[2] = bf2f(r.y & 0xffffu);
    dst[3] = bf2f(r.y >> 16);
}

// ---------------------------------------------------------------------------
// GEMM: C[m][n] = A[m][:] . W[:][n] + bias[n], fp32, 64x64 tile, BK=16.
// MODE 0: write bf16 to [B,H,T,D] layout (V path, no activation)
// MODE 1: same but with feature map elu(x)+1 (Q/K paths)
// MODE 2: write fp32 to standard [M,N] layout (output projection)
// ---------------------------------------------------------------------------
template <int MODE>
__global__ __launch_bounds__(256) void gemm_f32(
    const float* __restrict__ A, const float* __restrict__ W,
    const float* __restrict__ bias, unsigned short* __restrict__ outb,
    float* __restrict__ outf)
{
    __shared__ float As[16][64];   // [k][m]
    __shared__ float Bs[16][64];   // [k][n]

    const int tid = threadIdx.x;
    const int bx = blockIdx.x;     // n tile (16)
    const int by = blockIdx.y;     // m tile (128)
    const int tx = tid & 15, ty = tid >> 4;
    const int row0 = by * 64, col0 = bx * 64;

    float acc[4][4] = {};

    const float* Ap = A + (size_t)(row0 + (tid >> 2)) * KDIM + (tid & 3) * 4;
    const float* Wp = W + (size_t)(tid >> 4) * NDIM + col0 + (tid & 15) * 4;

    for (int k0 = 0; k0 < KDIM; k0 += 16) {
        float4 a4 = *(const float4*)(Ap + k0);
        float4 b4 = *(const float4*)(Wp + (size_t)k0 * NDIM);
        __syncthreads();                       // protect previous iter's reads
        const int ar = tid >> 2, ac = (tid & 3) * 4;
        As[ac + 0][ar] = a4.x;
        As[ac + 1][ar] = a4.y;
        As[ac + 2][ar] = a4.z;
        As[ac + 3][ar] = a4.w;
        *(float4*)&Bs[tid >> 4][(tid & 15) * 4] = b4;
        __syncthreads();
#pragma unroll
        for (int kk = 0; kk < 16; ++kk) {
            float4 av = *(const float4*)&As[kk][ty * 4];
            float4 bv = *(const float4*)&Bs[kk][tx * 4];
            acc[0][0] = fmaf(av.x, bv.x, acc[0][0]);
            acc[0][1] = fmaf(av.x, bv.y, acc[0][1]);
            acc[0][2] = fmaf(av.x, bv.z, acc[0][2]);
            acc[0][3] = fmaf(av.x, bv.w, acc[0][3]);
            acc[1][0] = fmaf(av.y, bv.x, acc[1][0]);
            acc[1][1] = fmaf(av.y, bv.y, acc[1][1]);
            acc[1][2] = fmaf(av.y, bv.z, acc[1][2]);
            acc[1][3] = fmaf(av.y, bv.w, acc[1][3]);
            acc[2][0] = fmaf(av.z, bv.x, acc[2][0]);
            acc[2][1] = fmaf(av.z, bv.y, acc[2][1]);
            acc[2][2] = fmaf(av.z, bv.z, acc[2][2]);
            acc[2][3] = fmaf(av.z, bv.w, acc[2][3]);
            acc[3][0] = fmaf(av.w, bv.x, acc[3][0]);
            acc[3][1] = fmaf(av.w, bv.y, acc[3][1]);
            acc[3][2] = fmaf(av.w, bv.z, acc[3][2]);
            acc[3][3] = fmaf(av.w, bv.w, acc[3][3]);
        }
    }

    float bvals[4];
#pragma unroll
    for (int j = 0; j < 4; ++j) bvals[j] = bias[col0 + tx * 4 + j];

#pragma unroll
    for (int i = 0; i < 4; ++i) {
        const int m = row0 + ty * 4 + i;
        float vv[4];
#pragma unroll
        for (int j = 0; j < 4; ++j) {
            float v = acc[i][j] + bvals[j];
            if (MODE == 1) v = (v > 0.f) ? (v + 1.f) : __expf(v);
            vv[j] = v;
        }
        if (MODE == 2) {
            const int n0 = col0 + tx * 4;
            *(float4*)&outf[(size_t)m * NDIM + n0] =
                make_float4(vv[0], vv[1], vv[2], vv[3]);
        } else {
            // tile is 64 cols wide and 64-aligned -> exactly one head per block
            const int bb = m >> 12;            // / T_
            const int t  = m & (T_ - 1);
            const int h  = col0 >> 6;
            const int d0 = tx * 4;
            const size_t base = ((((size_t)bb * H_ + h) * T_) + t) * D_ + d0;
            *(ushort4*)&outb[base] =
                make_ushort4(f2bf(vv[0]), f2bf(vv[1]), f2bf(vv[2]), f2bf(vv[3]));
        }
    }
}

// ---------------------------------------------------------------------------
// Phase A: per-chunk local sums  S_local = sum_t k_t (outer) v_t,  z_local = sum_t k_t
// grid = B*H*NC blocks, 256 threads. Thread (g = tid&3, e = tid>>2) owns
// S[d][e] for d = g*16 .. g*16+15.
// ---------------------------------------------------------------------------
__global__ __launch_bounds__(256) void chunk_sums(
    const unsigned short* __restrict__ Kb, const unsigned short* __restrict__ Vb,
    float* __restrict__ chunkS, float* __restrict__ chunkZ)
{
    __shared__ float k_lds[16][64];
    __shared__ float v_lds[16][64];

    const int tid = threadIdx.x;
    const int cid = blockIdx.x;
    const int bh = cid >> 5;       // NC = 32
    const int c  = cid & 31;
    const int g = tid & 3, e = tid >> 2;
    const int t0 = c * CT;

    float S[16] = {};
    float zacc = 0.f;              // meaningful for tid < 64

    const unsigned short* kp = Kb + ((size_t)bh * T_ + t0) * D_;
    const unsigned short* vp = Vb + ((size_t)bh * T_ + t0) * D_;

    for (int s0 = 0; s0 < CT; s0 += 16) {
        uint2 kraw = *(const uint2*)(kp + (size_t)s0 * 64 + tid * 4);
        uint2 vraw = *(const uint2*)(vp + (size_t)s0 * 64 + tid * 4);
        __syncthreads();
        decode4(kraw, &k_lds[0][0] + tid * 4);
        decode4(vraw, &v_lds[0][0] + tid * 4);
        __syncthreads();
#pragma unroll
        for (int tt = 0; tt < 16; ++tt) {
            float kv[16];
            const float4* kr = (const float4*)&k_lds[tt][g * 16];
            ((float4*)kv)[0] = kr[0];
            ((float4*)kv)[1] = kr[1];
            ((float4*)kv)[2] = kr[2];
            ((float4*)kv)[3] = kr[3];
            const float ve = v_lds[tt][e];
#pragma unroll
            for (int i = 0; i < 16; ++i) S[i] = fmaf(kv[i], ve, S[i]);
        }
        if (tid < 64) {
#pragma unroll
            for (int tt = 0; tt < 16; ++tt) zacc += k_lds[tt][tid];
        }
    }

    float* Sout = chunkS + ((size_t)bh * NC + c) * (D_ * D_);
#pragma unroll
    for (int i = 0; i < 16; ++i) Sout[(g * 16 + i) * 64 + e] = S[i];
    if (tid < 64) chunkZ[((size_t)bh * NC + c) * D_ + tid] = zacc;
}

// ---------------------------------------------------------------------------
// Phase B: in-place exclusive prefix over chunks (per b,h). 32 blocks.
// Elementwise over the flat 4096-float S matrix -> coalesced.
// ---------------------------------------------------------------------------
__global__ __launch_bounds__(256) void chunk_scan(
    float* __restrict__ chunkS, float* __restrict__ chunkZ)
{
    const int tid = threadIdx.x;
    const int bh = blockIdx.x;
    float acc[16] = {};
    float zacc = 0.f;
    float* Sb = chunkS + (size_t)bh * NC * (D_ * D_);
    float* Zb = chunkZ + (size_t)bh * NC * D_;
    for (int c = 0; c < NC; ++c) {
        float* p = Sb + (size_t)c * (D_ * D_);
#pragma unroll
        for (int j = 0; j < 16; ++j) {
            const float cur = p[tid + j * 256];
            p[tid + j * 256] = acc[j];
            acc[j] += cur;
        }
        if (tid < 64) {
            float* pz = Zb + (size_t)c * D_;
            const float cz = pz[tid];
            pz[tid] = zacc;
            zacc += cz;
        }
    }
}

// ---------------------------------------------------------------------------
// Phase C: in-chunk sequential recurrence from prefix state.
// grid = B*H*NC blocks, 256 threads, same (g,e) ownership as Phase A.
// den is computed redundantly per thread-quad via a replicated z (no 2nd barrier).
// ---------------------------------------------------------------------------
__global__ __launch_bounds__(256) void chunk_attn(
    const unsigned short* __restrict__ Qb, const unsigned short* __restrict__ Kb,
    const unsigned short* __restrict__ Vb,
    const float* __restrict__ chunkS, const float* __restrict__ chunkZ,
    float* __restrict__ att)
{
    __shared__ float q_lds[16][64];
    __shared__ float k_lds[16][64];
    __shared__ float v_lds[16][64];
    __shared__ float z_lds[64];

    const int tid = threadIdx.x;
    const int cid = blockIdx.x;
    const int bh = cid >> 5;
    const int c  = cid & 31;
    const int b  = bh >> 4, h = bh & 15;
    const int g = tid & 3, e = tid >> 2;
    const int t0 = c * CT;

    // initial state
    float S[16];
    const float* Sp = chunkS + ((size_t)bh * NC + c) * (D_ * D_);
#pragma unroll
    for (int i = 0; i < 16; ++i) S[i] = Sp[(g * 16 + i) * 64 + e];
    if (tid < 64) z_lds[tid] = chunkZ[((size_t)bh * NC + c) * D_ + tid];
    __syncthreads();
    float z[16];
#pragma unroll
    for (int i = 0; i < 16; ++i) z[i] = z_lds[g * 16 + i];

    const unsigned short* qp = Qb + ((size_t)bh * T_ + t0) * D_;
    const unsigned short* kp = Kb + ((size_t)bh * T_ + t0) * D_;
    const unsigned short* vp = Vb + ((size_t)bh * T_ + t0) * D_;

    float* outp = att + ((size_t)b * T_ + t0) * E_ + h * D_ + e;
    const bool writer = (g == 0);

    for (int s0 = 0; s0 < CT; s0 += 16) {
        uint2 qraw = *(const uint2*)(qp + (size_t)s0 * 64 + tid * 4);
        uint2 kraw = *(const uint2*)(kp + (size_t)s0 * 64 + tid * 4);
        uint2 vraw = *(const uint2*)(vp + (size_t)s0 * 64 + tid * 4);
        __syncthreads();
        decode4(qraw, &q_lds[0][0] + tid * 4);
        decode4(kraw, &k_lds[0][0] + tid * 4);
        decode4(vraw, &v_lds[0][0] + tid * 4);
        __syncthreads();
#pragma unroll
        for (int tt = 0; tt < 16; ++tt) {
            float kv[16], qv[16];
            const float4* kr = (const float4*)&k_lds[tt][g * 16];
            const float4* qr = (const float4*)&q_lds[tt][g * 16];
            ((float4*)kv)[0] = kr[0];
            ((float4*)kv)[1] = kr[1];
            ((float4*)kv)[2] = kr[2];
            ((float4*)kv)[3] = kr[3];
            ((float4*)qv)[0] = qr[0];
            ((float4*)qv)[1] = qr[1];
            ((float4*)qv)[2] = qr[2];
            ((float4*)qv)[3] = qr[3];
            const float ve = v_lds[tt][e];
            float pn = 0.f, pd = 0.f;
#pragma unroll
            for (int i = 0; i < 16; ++i) {
                S[i] = fmaf(kv[i], ve, S[i]);   // S += k (outer) v
                z[i] += kv[i];                  // z += k (replicated copy)
                pn = fmaf(qv[i], S[i], pn);     // q . S[:,e] partial
                pd = fmaf(qv[i], z[i], pd);     // q . z partial
            }
            pn += __shfl_xor(pn, 1);
            pn += __shfl_xor(pn, 2);
            pd += __shfl_xor(pd, 1);
            pd += __shfl_xor(pd, 2);
            if (writer) outp[(size_t)(s0 + tt) * E_] = pn / (pd + EPSC);
        }
    }
}

// ---------------------------------------------------------------------------
extern "C" void kernel_launch(void* const* d_in, const int* in_sizes, int n_in,
                              void* d_out, int out_size, void* d_ws, size_t ws_size,
                              hipStream_t stream)
{
    const float* x  = (const float*)d_in[0];
    const float* wq = (const float*)d_in[1];
    const float* bq = (const float*)d_in[2];
    const float* wk = (const float*)d_in[3];
    const float* bk = (const float*)d_in[4];
    const float* wv = (const float*)d_in[5];
    const float* bv = (const float*)d_in[6];
    const float* wo = (const float*)d_in[7];
    const float* bo = (const float*)d_in[8];
    float* out = (float*)d_out;

    // workspace layout (bytes):
    //   0        q  bf16 [B,H,T,D]   16 MB
    //   16 MB    k  bf16             16 MB
    //   32 MB    v  bf16             16 MB
    //   48 MB    att f32 [B,T,E]     32 MB
    //   80 MB    chunkS f32          16 MB
    //   96 MB    chunkZ f32          256 KB
    char* ws = (char*)d_ws;
    unsigned short* qb = (unsigned short*)(ws);
    unsigned short* kb = (unsigned short*)(ws + (size_t)16 * 1024 * 1024);
    unsigned short* vb = (unsigned short*)(ws + (size_t)32 * 1024 * 1024);
    float* att = (float*)(ws + (size_t)48 * 1024 * 1024);
    float* cS  = (float*)(ws + (size_t)80 * 1024 * 1024);
    float* cZ  = (float*)(ws + (size_t)96 * 1024 * 1024);

    const dim3 gg(NDIM / 64, M_ / 64);
    gemm_f32<1><<<gg, 256, 0, stream>>>(x, wq, bq, qb, nullptr);
    gemm_f32<1><<<gg, 256, 0, stream>>>(x, wk, bk, kb, nullptr);
    gemm_f32<0><<<gg, 256, 0, stream>>>(x, wv, bv, vb, nullptr);

    chunk_sums<<<B_ * H_ * NC, 256, 0, stream>>>(kb, vb, cS, cZ);
    chunk_scan<<<B_ * H_, 256, 0, stream>>>(cS, cZ);
    chunk_attn<<<B_ * H_ * NC, 256, 0, stream>>>(qb, kb, vb, cS, cZ, att);

    gemm_f32<2><<<gg, 256, 0, stream>>>(att, wo, bo, nullptr, out);
}

// Round 2
// 295.474 us; speedup vs baseline: 3.9650x; 3.9650x over previous
//
#include <hip/hip_runtime.h>
#include <hip/hip_bf16.h>
#include <cstdint>
#include <cstddef>

// Problem constants
#define B_   2
#define T_   4096
#define E_   1024
#define H_   16
#define D_   64
#define M_   (B_ * T_)       // 8192 rows
#define KDIM 1024
#define NDIM 1024
#define EPSC 1e-6f
#define CT   128             // chunk length for the recurrence
#define NC   (T_ / CT)       // 32 chunks per (b,h)

typedef __attribute__((ext_vector_type(8))) short bf16x8;
typedef __attribute__((ext_vector_type(4))) float f32x4;

// ---------- small helpers ----------
__device__ __forceinline__ float bf2f(uint32_t u) {
    union { uint32_t u; float f; } x; x.u = u << 16; return x.f;
}
__device__ __forceinline__ unsigned short f2bf(float f) {
    union { float f; uint32_t u; } x; x.f = f;
    uint32_t r = x.u + 0x7fffu + ((x.u >> 16) & 1u);   // round-to-nearest-even
    return (unsigned short)(r >> 16);
}
__device__ __forceinline__ void decode4(uint2 r, float* dst) {
    dst[0] = bf2f(r.x & 0xffffu);
    dst[1] = bf2f(r.x >> 16);
    dst[2] = bf2f(r.y & 0xffffu);
    dst[3] = bf2f(r.y >> 16);
}
__device__ __forceinline__ void gload16(const void* g, void* l) {
    __builtin_amdgcn_global_load_lds(
        (const __attribute__((address_space(1))) void*)g,
        (__attribute__((address_space(3))) void*)l, 16, 0, 0);
}

// ---------------------------------------------------------------------------
// fp32 -> bf16 bulk convert (x). Each thread: 8 floats.
// ---------------------------------------------------------------------------
__global__ __launch_bounds__(256) void conv_bf16(
    const float* __restrict__ in, unsigned short* __restrict__ out)
{
    const int i = blockIdx.x * 256 + threadIdx.x;
    const float4* p = (const float4*)in;
    float4 a = p[i * 2], b = p[i * 2 + 1];
    ushort4 o0 = make_ushort4(f2bf(a.x), f2bf(a.y), f2bf(a.z), f2bf(a.w));
    ushort4 o1 = make_ushort4(f2bf(b.x), f2bf(b.y), f2bf(b.z), f2bf(b.w));
    *(ushort4*)&out[(size_t)i * 8] = o0;
    *(ushort4*)&out[(size_t)i * 8 + 4] = o1;
}

// ---------------------------------------------------------------------------
// Transpose + convert the four 1024x1024 fp32 weights to bf16 [N][K].
// 64x64 tiles, LDS padded to kill bank conflicts.
// ---------------------------------------------------------------------------
__global__ __launch_bounds__(256) void transpose_w4(
    const float* __restrict__ w0, const float* __restrict__ w1,
    const float* __restrict__ w2, const float* __restrict__ w3,
    unsigned short* __restrict__ o0, unsigned short* __restrict__ o1,
    unsigned short* __restrict__ o2, unsigned short* __restrict__ o3)
{
    const float* src; unsigned short* dst;
    switch (blockIdx.z) {
        case 0: src = w0; dst = o0; break;
        case 1: src = w1; dst = o1; break;
        case 2: src = w2; dst = o2; break;
        default: src = w3; dst = o3; break;
    }
    __shared__ float tile[64][65];
    const int t = threadIdx.x, tx = t & 63, ty = t >> 6;
    const int r0 = blockIdx.y * 64, c0 = blockIdx.x * 64;
#pragma unroll
    for (int i = 0; i < 16; ++i)
        tile[ty + i * 4][tx] = src[(size_t)(r0 + ty + i * 4) * KDIM + c0 + tx];
    __syncthreads();
#pragma unroll
    for (int i = 0; i < 16; ++i)
        dst[(size_t)(c0 + ty + i * 4) * KDIM + r0 + tx] = f2bf(tile[tx][ty + i * 4]);
}

// ---------------------------------------------------------------------------
// bf16 MFMA GEMM, m97 structure: 128x128 tile, BK=32, 4 waves (2x2),
// global_load_lds width=16, C = A[M][K] . Bt[N][K]^T + bias.
// MODE 1: feature map elu+1, bf16 out to [B,H,T,D]   (Q, K)
// MODE 0: bf16 out to [B,H,T,D]                      (V)
// MODE 2: f32 out to [M][N]                          (final projection)
// ---------------------------------------------------------------------------
template <int MODE>
__global__ __launch_bounds__(256) void gemm_bf16(
    const unsigned short* __restrict__ A,   // [M][1024] bf16
    const unsigned short* __restrict__ Bt,  // [1024][1024] bf16 (N-major)
    const float* __restrict__ bias,         // [1024] fp32
    unsigned short* __restrict__ outb, float* __restrict__ outf)
{
    __shared__ unsigned short As[128 * 32];   // [row][k] linear, 8 KB
    __shared__ unsigned short Bs[128 * 32];

    const int tid  = threadIdx.x;
    const int lane = tid & 63;
    const int wave = tid >> 6;
    const int wr = wave >> 1, wc = wave & 1;  // wave -> 64x64 sub-tile
    const int row0 = blockIdx.y * 128;
    const int col0 = blockIdx.x * 128;

    f32x4 acc[4][4] = {};

    // staging: thread t covers 16B at linear LDS offset t*16 (issue 0),
    // (256+t)*16 (issue 1) -> global row (i*256+t)/4, k-elems (t&3)*8
    const unsigned short* Ag = A  + (size_t)(row0 + (tid >> 2)) * KDIM + (tid & 3) * 8;
    const unsigned short* Bg = Bt + (size_t)(col0 + (tid >> 2)) * KDIM + (tid & 3) * 8;
    unsigned short* AsW = As + wave * 512;    // wave-uniform LDS base, issue 0
    unsigned short* BsW = Bs + wave * 512;

    const int fr = lane & 15;                 // fragment row
    const int fk = (lane >> 4) * 8;           // fragment k-offset (elements)

    for (int k0 = 0; k0 < KDIM; k0 += 32) {
        gload16(Ag + k0,              AsW);
        gload16(Ag + 64 * KDIM + k0,  AsW + 2048);
        gload16(Bg + k0,              BsW);
        gload16(Bg + 64 * KDIM + k0,  BsW + 2048);
        __syncthreads();                      // drains vmcnt -> tiles ready

        bf16x8 af[4], bfr[4];
#pragma unroll
        for (int m = 0; m < 4; ++m)
            af[m] = *(const bf16x8*)&As[(wr * 64 + m * 16 + fr) * 32 + fk];
#pragma unroll
        for (int n = 0; n < 4; ++n)
            bfr[n] = *(const bf16x8*)&Bs[(wc * 64 + n * 16 + fr) * 32 + fk];
#pragma unroll
        for (int m = 0; m < 4; ++m)
#pragma unroll
            for (int n = 0; n < 4; ++n)
                acc[m][n] = __builtin_amdgcn_mfma_f32_16x16x32_bf16(
                    af[m], bfr[n], acc[m][n], 0, 0, 0);
        __syncthreads();                      // all reads done before restage
    }

    // epilogue: C/D mapping col=lane&15, row=(lane>>4)*4+j  [m89/m91 verified]
    const int fcol = lane & 15;
    const int frow = (lane >> 4) * 4;
#pragma unroll
    for (int m = 0; m < 4; ++m) {
#pragma unroll
        for (int n = 0; n < 4; ++n) {
            const int col = col0 + wc * 64 + n * 16 + fcol;
            const float bval = bias[col];
#pragma unroll
            for (int j = 0; j < 4; ++j) {
                const int row = row0 + wr * 64 + m * 16 + frow + j;
                float v = acc[m][n][j] + bval;
                if (MODE == 1) v = (v > 0.f) ? (v + 1.f) : __expf(v);
                if (MODE == 2) {
                    outf[(size_t)row * NDIM + col] = v;
                } else {
                    const int bb = row >> 12;          // / T_
                    const int tt = row & (T_ - 1);
                    const int h  = col >> 6;
                    const int d  = col & 63;
                    outb[((((size_t)bb * H_ + h) * T_) + tt) * D_ + d] = f2bf(v);
                }
            }
        }
    }
}

// ---------------------------------------------------------------------------
// Phase A: per-chunk local sums  S_local = sum_t k_t (outer) v_t,  z_local = sum_t k_t
// ---------------------------------------------------------------------------
__global__ __launch_bounds__(256) void chunk_sums(
    const unsigned short* __restrict__ Kb, const unsigned short* __restrict__ Vb,
    float* __restrict__ chunkS, float* __restrict__ chunkZ)
{
    __shared__ float k_lds[16][64];
    __shared__ float v_lds[16][64];

    const int tid = threadIdx.x;
    const int cid = blockIdx.x;
    const int bh = cid >> 5;       // NC = 32
    const int c  = cid & 31;
    const int g = tid & 3, e = tid >> 2;
    const int t0 = c * CT;

    float S[16] = {};
    float zacc = 0.f;

    const unsigned short* kp = Kb + ((size_t)bh * T_ + t0) * D_;
    const unsigned short* vp = Vb + ((size_t)bh * T_ + t0) * D_;

    for (int s0 = 0; s0 < CT; s0 += 16) {
        uint2 kraw = *(const uint2*)(kp + (size_t)s0 * 64 + tid * 4);
        uint2 vraw = *(const uint2*)(vp + (size_t)s0 * 64 + tid * 4);
        __syncthreads();
        decode4(kraw, &k_lds[0][0] + tid * 4);
        decode4(vraw, &v_lds[0][0] + tid * 4);
        __syncthreads();
#pragma unroll
        for (int tt = 0; tt < 16; ++tt) {
            float kv[16];
            const float4* kr = (const float4*)&k_lds[tt][g * 16];
            ((float4*)kv)[0] = kr[0];
            ((float4*)kv)[1] = kr[1];
            ((float4*)kv)[2] = kr[2];
            ((float4*)kv)[3] = kr[3];
            const float ve = v_lds[tt][e];
#pragma unroll
            for (int i = 0; i < 16; ++i) S[i] = fmaf(kv[i], ve, S[i]);
        }
        if (tid < 64) {
#pragma unroll
            for (int tt = 0; tt < 16; ++tt) zacc += k_lds[tt][tid];
        }
    }

    float* Sout = chunkS + ((size_t)bh * NC + c) * (D_ * D_);
#pragma unroll
    for (int i = 0; i < 16; ++i) Sout[(g * 16 + i) * 64 + e] = S[i];
    if (tid < 64) chunkZ[((size_t)bh * NC + c) * D_ + tid] = zacc;
}

// ---------------------------------------------------------------------------
// Phase B: in-place exclusive prefix over chunks (per b,h).
// ---------------------------------------------------------------------------
__global__ __launch_bounds__(256) void chunk_scan(
    float* __restrict__ chunkS, float* __restrict__ chunkZ)
{
    const int tid = threadIdx.x;
    const int bh = blockIdx.x;
    float acc[16] = {};
    float zacc = 0.f;
    float* Sb = chunkS + (size_t)bh * NC * (D_ * D_);
    float* Zb = chunkZ + (size_t)bh * NC * D_;
    for (int c = 0; c < NC; ++c) {
        float* p = Sb + (size_t)c * (D_ * D_);
#pragma unroll
        for (int j = 0; j < 16; ++j) {
            const float cur = p[tid + j * 256];
            p[tid + j * 256] = acc[j];
            acc[j] += cur;
        }
        if (tid < 64) {
            float* pz = Zb + (size_t)c * D_;
            const float cz = pz[tid];
            pz[tid] = zacc;
            zacc += cz;
        }
    }
}

// ---------------------------------------------------------------------------
// Phase C: in-chunk sequential recurrence from prefix state; writes att bf16 [M][E].
// ---------------------------------------------------------------------------
__global__ __launch_bounds__(256) void chunk_attn(
    const unsigned short* __restrict__ Qb, const unsigned short* __restrict__ Kb,
    const unsigned short* __restrict__ Vb,
    const float* __restrict__ chunkS, const float* __restrict__ chunkZ,
    unsigned short* __restrict__ att)
{
    __shared__ float q_lds[16][64];
    __shared__ float k_lds[16][64];
    __shared__ float v_lds[16][64];
    __shared__ float z_lds[64];

    const int tid = threadIdx.x;
    const int cid = blockIdx.x;
    const int bh = cid >> 5;
    const int c  = cid & 31;
    const int b  = bh >> 4, h = bh & 15;
    const int g = tid & 3, e = tid >> 2;
    const int t0 = c * CT;

    float S[16];
    const float* Sp = chunkS + ((size_t)bh * NC + c) * (D_ * D_);
#pragma unroll
    for (int i = 0; i < 16; ++i) S[i] = Sp[(g * 16 + i) * 64 + e];
    if (tid < 64) z_lds[tid] = chunkZ[((size_t)bh * NC + c) * D_ + tid];
    __syncthreads();
    float z[16];
#pragma unroll
    for (int i = 0; i < 16; ++i) z[i] = z_lds[g * 16 + i];

    const unsigned short* qp = Qb + ((size_t)bh * T_ + t0) * D_;
    const unsigned short* kp = Kb + ((size_t)bh * T_ + t0) * D_;
    const unsigned short* vp = Vb + ((size_t)bh * T_ + t0) * D_;

    unsigned short* outp = att + ((size_t)(b * T_ + t0)) * E_ + h * D_ + e;
    const bool writer = (g == 0);

    for (int s0 = 0; s0 < CT; s0 += 16) {
        uint2 qraw = *(const uint2*)(qp + (size_t)s0 * 64 + tid * 4);
        uint2 kraw = *(const uint2*)(kp + (size_t)s0 * 64 + tid * 4);
        uint2 vraw = *(const uint2*)(vp + (size_t)s0 * 64 + tid * 4);
        __syncthreads();
        decode4(qraw, &q_lds[0][0] + tid * 4);
        decode4(kraw, &k_lds[0][0] + tid * 4);
        decode4(vraw, &v_lds[0][0] + tid * 4);
        __syncthreads();
#pragma unroll
        for (int tt = 0; tt < 16; ++tt) {
            float kv[16], qv[16];
            const float4* kr = (const float4*)&k_lds[tt][g * 16];
            const float4* qr = (const float4*)&q_lds[tt][g * 16];
            ((float4*)kv)[0] = kr[0];
            ((float4*)kv)[1] = kr[1];
            ((float4*)kv)[2] = kr[2];
            ((float4*)kv)[3] = kr[3];
            ((float4*)qv)[0] = qr[0];
            ((float4*)qv)[1] = qr[1];
            ((float4*)qv)[2] = qr[2];
            ((float4*)qv)[3] = qr[3];
            const float ve = v_lds[tt][e];
            float pn = 0.f, pd = 0.f;
#pragma unroll
            for (int i = 0; i < 16; ++i) {
                S[i] = fmaf(kv[i], ve, S[i]);
                z[i] += kv[i];
                pn = fmaf(qv[i], S[i], pn);
                pd = fmaf(qv[i], z[i], pd);
            }
            pn += __shfl_xor(pn, 1);
            pn += __shfl_xor(pn, 2);
            pd += __shfl_xor(pd, 1);
            pd += __shfl_xor(pd, 2);
            if (writer) outp[(size_t)(s0 + tt) * E_] = f2bf(pn / (pd + EPSC));
        }
    }
}

// ---------------------------------------------------------------------------
extern "C" void kernel_launch(void* const* d_in, const int* in_sizes, int n_in,
                              void* d_out, int out_size, void* d_ws, size_t ws_size,
                              hipStream_t stream)
{
    const float* x  = (const float*)d_in[0];
    const float* wq = (const float*)d_in[1];
    const float* bq = (const float*)d_in[2];
    const float* wk = (const float*)d_in[3];
    const float* bk = (const float*)d_in[4];
    const float* wv = (const float*)d_in[5];
    const float* bv = (const float*)d_in[6];
    const float* wo = (const float*)d_in[7];
    const float* bo = (const float*)d_in[8];
    float* out = (float*)d_out;

    // workspace layout (bytes):
    //   0      qb  bf16 [B,H,T,D]           16 MB
    //   16 MB  kb  bf16                     16 MB
    //   32 MB  vb  bf16                     16 MB
    //   48 MB  xb  bf16 [M][K]  (GEMM in)   16 MB  -- later aliased by attb
    //   64 MB  cS  f32                      16 MB
    //   80 MB  cZ  f32                     256 KB
    //   80.25  wT  bf16 x4 (transposed)      8 MB
    // total 88.25 MB (round 1 proved ws >= 96.25 MB)
    char* ws = (char*)d_ws;
    unsigned short* qb = (unsigned short*)(ws);
    unsigned short* kb = (unsigned short*)(ws + (size_t)16 * 1024 * 1024);
    unsigned short* vb = (unsigned short*)(ws + (size_t)32 * 1024 * 1024);
    unsigned short* xb = (unsigned short*)(ws + (size_t)48 * 1024 * 1024);
    unsigned short* attb = xb;  // alias: xb dead after V GEMM, attb written after
    float* cS = (float*)(ws + (size_t)64 * 1024 * 1024);
    float* cZ = (float*)(ws + (size_t)80 * 1024 * 1024);
    unsigned short* wqT = (unsigned short*)(ws + (size_t)80 * 1024 * 1024 + 256 * 1024);
    unsigned short* wkT = wqT + (size_t)KDIM * NDIM;
    unsigned short* wvT = wkT + (size_t)KDIM * NDIM;
    unsigned short* woT = wvT + (size_t)KDIM * NDIM;

    conv_bf16<<<M_ * KDIM / (256 * 8), 256, 0, stream>>>(x, xb);
    transpose_w4<<<dim3(16, 16, 4), 256, 0, stream>>>(wq, wk, wv, wo,
                                                      wqT, wkT, wvT, woT);

    const dim3 gg(NDIM / 128, M_ / 128);
    gemm_bf16<1><<<gg, 256, 0, stream>>>(xb, wqT, bq, qb, nullptr);
    gemm_bf16<1><<<gg, 256, 0, stream>>>(xb, wkT, bk, kb, nullptr);
    gemm_bf16<0><<<gg, 256, 0, stream>>>(xb, wvT, bv, vb, nullptr);

    chunk_sums<<<B_ * H_ * NC, 256, 0, stream>>>(kb, vb, cS, cZ);
    chunk_scan<<<B_ * H_, 256, 0, stream>>>(cS, cZ);
    chunk_attn<<<B_ * H_ * NC, 256, 0, stream>>>(qb, kb, vb, cS, cZ, attb);

    gemm_bf16<2><<<gg, 256, 0, stream>>>(attb, woT, bo, nullptr, out);
}

// Round 3
// 189.855 us; speedup vs baseline: 6.1707x; 1.5563x over previous
//
#include <hip/hip_runtime.h>
#include <hip/hip_bf16.h>
#include <cstdint>
#include <cstddef>

// Problem constants
#define B_   2
#define T_   4096
#define E_   1024
#define H_   16
#define D_   64
#define M_   (B_ * T_)       // 8192 rows
#define KDIM 1024
#define NDIM 1024
#define EPSC 1e-6f
#define CT   128             // chunk length
#define NC   (T_ / CT)       // 32 chunks per (b,h)

typedef __attribute__((ext_vector_type(8))) short bf16x8;
typedef __attribute__((ext_vector_type(4))) float f32x4;

// ---------- small helpers ----------
__device__ __forceinline__ float bf2f(uint32_t u) {
    union { uint32_t u; float f; } x; x.u = u << 16; return x.f;
}
__device__ __forceinline__ unsigned short f2bf(float f) {
    union { float f; uint32_t u; } x; x.f = f;
    uint32_t r = x.u + 0x7fffu + ((x.u >> 16) & 1u);   // RNE
    return (unsigned short)(r >> 16);
}
__device__ __forceinline__ void gload16(const void* g, void* l) {
    __builtin_amdgcn_global_load_lds(
        (const __attribute__((address_space(1))) void*)g,
        (__attribute__((address_space(3))) void*)l, 16, 0, 0);
}

// ---------------------------------------------------------------------------
// fp32 -> bf16 bulk convert (x). Each thread: 8 floats.
// ---------------------------------------------------------------------------
__global__ __launch_bounds__(256) void conv_bf16(
    const float* __restrict__ in, unsigned short* __restrict__ out)
{
    const int i = blockIdx.x * 256 + threadIdx.x;
    const float4* p = (const float4*)in;
    float4 a = p[i * 2], b = p[i * 2 + 1];
    ushort4 o0 = make_ushort4(f2bf(a.x), f2bf(a.y), f2bf(a.z), f2bf(a.w));
    ushort4 o1 = make_ushort4(f2bf(b.x), f2bf(b.y), f2bf(b.z), f2bf(b.w));
    *(ushort4*)&out[(size_t)i * 8] = o0;
    *(ushort4*)&out[(size_t)i * 8 + 4] = o1;
}

// ---------------------------------------------------------------------------
// Transpose + convert the four 1024x1024 fp32 weights to bf16 [N][K].
// ---------------------------------------------------------------------------
__global__ __launch_bounds__(256) void transpose_w4(
    const float* __restrict__ w0, const float* __restrict__ w1,
    const float* __restrict__ w2, const float* __restrict__ w3,
    unsigned short* __restrict__ o0, unsigned short* __restrict__ o1,
    unsigned short* __restrict__ o2, unsigned short* __restrict__ o3)
{
    const float* src; unsigned short* dst;
    switch (blockIdx.z) {
        case 0: src = w0; dst = o0; break;
        case 1: src = w1; dst = o1; break;
        case 2: src = w2; dst = o2; break;
        default: src = w3; dst = o3; break;
    }
    __shared__ float tile[64][65];
    const int t = threadIdx.x, tx = t & 63, ty = t >> 6;
    const int r0 = blockIdx.y * 64, c0 = blockIdx.x * 64;
#pragma unroll
    for (int i = 0; i < 16; ++i)
        tile[ty + i * 4][tx] = src[(size_t)(r0 + ty + i * 4) * KDIM + c0 + tx];
    __syncthreads();
#pragma unroll
    for (int i = 0; i < 16; ++i)
        dst[(size_t)(c0 + ty + i * 4) * KDIM + r0 + tx] = f2bf(tile[tx][ty + i * 4]);
}

// ---------------------------------------------------------------------------
// bf16 MFMA GEMM (m97 structure): 128x128 tile, BK=32, 4 waves.
// MODE 1: feature map, bf16 row-major [B,H,T,D]           (Q)
// MODE 3: feature map, row-major [B,H,T,D] + transposed [B,H,D,T]  (K)
// MODE 0: no act, transposed [B,H,D,T] only               (V)
// MODE 2: f32 [M][N]                                      (out proj)
// ---------------------------------------------------------------------------
template <int MODE>
__global__ __launch_bounds__(256) void gemm_bf16(
    const unsigned short* __restrict__ A,   // [M][1024] bf16
    const unsigned short* __restrict__ Bt,  // [1024][1024] bf16 (N-major)
    const float* __restrict__ bias,
    unsigned short* __restrict__ outb,      // row-major [B,H,T,D]
    unsigned short* __restrict__ outb2,     // transposed [B,H,D,T]
    float* __restrict__ outf)
{
    __shared__ unsigned short As[128 * 32];
    __shared__ unsigned short Bs[128 * 32];

    const int tid  = threadIdx.x;
    const int lane = tid & 63;
    const int wave = tid >> 6;
    const int wr = wave >> 1, wc = wave & 1;
    const int row0 = blockIdx.y * 128;
    const int col0 = blockIdx.x * 128;

    f32x4 acc[4][4] = {};

    const unsigned short* Ag = A  + (size_t)(row0 + (tid >> 2)) * KDIM + (tid & 3) * 8;
    const unsigned short* Bg = Bt + (size_t)(col0 + (tid >> 2)) * KDIM + (tid & 3) * 8;
    unsigned short* AsW = As + wave * 512;
    unsigned short* BsW = Bs + wave * 512;

    const int fr = lane & 15;
    const int fk = (lane >> 4) * 8;

    for (int k0 = 0; k0 < KDIM; k0 += 32) {
        gload16(Ag + k0,              AsW);
        gload16(Ag + 64 * KDIM + k0,  AsW + 2048);
        gload16(Bg + k0,              BsW);
        gload16(Bg + 64 * KDIM + k0,  BsW + 2048);
        __syncthreads();

        bf16x8 af[4], bfr[4];
#pragma unroll
        for (int m = 0; m < 4; ++m)
            af[m] = *(const bf16x8*)&As[(wr * 64 + m * 16 + fr) * 32 + fk];
#pragma unroll
        for (int n = 0; n < 4; ++n)
            bfr[n] = *(const bf16x8*)&Bs[(wc * 64 + n * 16 + fr) * 32 + fk];
#pragma unroll
        for (int m = 0; m < 4; ++m)
#pragma unroll
            for (int n = 0; n < 4; ++n)
                acc[m][n] = __builtin_amdgcn_mfma_f32_16x16x32_bf16(
                    af[m], bfr[n], acc[m][n], 0, 0, 0);
        __syncthreads();
    }

    const int fcol = lane & 15;
    const int frow = (lane >> 4) * 4;
#pragma unroll
    for (int m = 0; m < 4; ++m) {
#pragma unroll
        for (int n = 0; n < 4; ++n) {
            const int col = col0 + wc * 64 + n * 16 + fcol;
            const float bval = bias[col];
            const int rbase = row0 + wr * 64 + m * 16 + frow;
            float vv[4];
#pragma unroll
            for (int j = 0; j < 4; ++j) {
                float v = acc[m][n][j] + bval;
                if (MODE == 1 || MODE == 3) v = (v > 0.f) ? (v + 1.f) : __expf(v);
                vv[j] = v;
            }
            if (MODE == 2) {
#pragma unroll
                for (int j = 0; j < 4; ++j)
                    outf[(size_t)(rbase + j) * NDIM + col] = vv[j];
            } else {
                const int h = col >> 6;
                const int d = col & 63;
                if (MODE == 1 || MODE == 3) {
#pragma unroll
                    for (int j = 0; j < 4; ++j) {
                        const int row = rbase + j;
                        const int bb = row >> 12;
                        const int tt = row & (T_ - 1);
                        outb[((((size_t)bb * H_ + h) * T_) + tt) * D_ + d] = f2bf(vv[j]);
                    }
                }
                if (MODE == 0 || MODE == 3) {
                    const int bb = rbase >> 12;
                    const int tt = rbase & (T_ - 1);
                    ushort4 tp = make_ushort4(f2bf(vv[0]), f2bf(vv[1]),
                                              f2bf(vv[2]), f2bf(vv[3]));
                    *(ushort4*)&outb2[(((size_t)bb * H_ + h) * D_ + d) * T_ + tt] = tp;
                }
            }
        }
    }
}

// ---------------------------------------------------------------------------
// Phase A (MFMA): per-chunk S_local = K^T V (+ z via ones-cols), bf16 out.
// Sl layout: [bh*NC + c][e][d] (transposed, ready as B^T frags later).
// ---------------------------------------------------------------------------
__global__ __launch_bounds__(256) void chunk_sums_mfma(
    const unsigned short* __restrict__ Kt,  // [BH][64][T]
    const unsigned short* __restrict__ Vt,  // [BH][64][T]
    unsigned short* __restrict__ Sl,        // [BH*NC][64*64]
    unsigned short* __restrict__ Zl)        // [BH*NC][64]
{
    const int tid = threadIdx.x, lane = tid & 63, w = tid >> 6;
    const int lo = lane & 15, hi = lane >> 4;
    const int cid = blockIdx.x, bh = cid >> 5, c = cid & 31, t0 = c * CT;
    const unsigned short* kT = Kt + (size_t)bh * 64 * T_ + t0;
    const unsigned short* vT = Vt + (size_t)bh * 64 * T_ + t0;

    const bf16x8 ones8 = {0x3F80, 0x3F80, 0x3F80, 0x3F80,
                          0x3F80, 0x3F80, 0x3F80, 0x3F80};
    f32x4 acc[5] = {};
#pragma unroll
    for (int kt = 0; kt < 4; ++kt) {
        bf16x8 af = *(const bf16x8*)&kT[(size_t)(w * 16 + lo) * T_ + kt * 32 + hi * 8];
        bf16x8 bfr[5];
#pragma unroll
        for (int et = 0; et < 4; ++et)
            bfr[et] = *(const bf16x8*)&vT[(size_t)(et * 16 + lo) * T_ + kt * 32 + hi * 8];
        bfr[4] = ones8;   // all rows = ones -> every col 64..79 equals z
#pragma unroll
        for (int et = 0; et < 5; ++et)
            acc[et] = __builtin_amdgcn_mfma_f32_16x16x32_bf16(af, bfr[et], acc[et], 0, 0, 0);
    }
    unsigned short* sO = Sl + (size_t)cid * 4096;
    const int d0 = w * 16 + hi * 4;
#pragma unroll
    for (int et = 0; et < 4; ++et) {
        const int e = et * 16 + lo;
        ushort4 pk = make_ushort4(f2bf(acc[et][0]), f2bf(acc[et][1]),
                                  f2bf(acc[et][2]), f2bf(acc[et][3]));
        *(ushort4*)&sO[e * 64 + d0] = pk;   // [e][d] layout, d contiguous
    }
    if (lo == 0) {
        ushort4 pk = make_ushort4(f2bf(acc[4][0]), f2bf(acc[4][1]),
                                  f2bf(acc[4][2]), f2bf(acc[4][3]));
        *(ushort4*)&Zl[(size_t)cid * 64 + d0] = pk;
    }
}

// ---------------------------------------------------------------------------
// Phase B: in-place exclusive prefix over chunks, bf16, f32 accumulation.
// grid (8 slices, 32 bh); slice 0 also scans z.
// ---------------------------------------------------------------------------
__global__ __launch_bounds__(256) void chunk_scan_bf(
    unsigned short* __restrict__ S, unsigned short* __restrict__ Z)
{
    const int bh = blockIdx.y;
    const int f0 = blockIdx.x * 512 + threadIdx.x * 2;
    float a0 = 0.f, a1 = 0.f;
    unsigned short* base = S + (size_t)bh * NC * 4096 + f0;
    for (int c = 0; c < NC; ++c) {
        uint32_t* p = (uint32_t*)(base + (size_t)c * 4096);
        uint32_t v = *p;
        float c0 = bf2f(v & 0xffffu), c1 = bf2f(v >> 16);
        *p = (uint32_t)f2bf(a0) | ((uint32_t)f2bf(a1) << 16);
        a0 += c0; a1 += c1;
    }
    if (blockIdx.x == 0 && threadIdx.x < 32) {
        float b0 = 0.f, b1 = 0.f;
        unsigned short* zb = Z + (size_t)bh * NC * 64 + threadIdx.x * 2;
        for (int c = 0; c < NC; ++c) {
            uint32_t* p = (uint32_t*)(zb + (size_t)c * 64);
            uint32_t v = *p;
            float c0 = bf2f(v & 0xffffu), c1 = bf2f(v >> 16);
            *p = (uint32_t)f2bf(b0) | ((uint32_t)f2bf(b1) << 16);
            b0 += c0; b1 += c1;
        }
    }
}

// ---------------------------------------------------------------------------
// Phase C (MFMA): per chunk,
//   P^T = K.Q^T (masked s<=t, bf16, LDS swizzled [t][s])
//   numext = Q.[Sp|z] + P.[V|1]  -> cols 64..79 all = den (replicated trick)
//   att[t][h*64+e] = num/(den+eps), staged via LDS for coalesced writes.
// ---------------------------------------------------------------------------
__global__ __launch_bounds__(256) void chunk_attn_mfma(
    const unsigned short* __restrict__ Qb,  // [BH][T][64] row-major
    const unsigned short* __restrict__ Kb,  // [BH][T][64] row-major
    const unsigned short* __restrict__ Vt,  // [BH][64][T] transposed
    const unsigned short* __restrict__ SpT, // [BH*NC][64*64] prefix [e][d]
    const unsigned short* __restrict__ Zp,  // [BH*NC][64] prefix
    unsigned short* __restrict__ att)       // [M][1024]
{
    __shared__ unsigned short lds[128 * 128];   // 32KB: Pt, then out-stage

    const int tid = threadIdx.x;
    const int lane = tid & 63;
    const int w = tid >> 6;
    const int lo = lane & 15, hi = lane >> 4;
    const int cid = blockIdx.x;
    const int bh = cid >> 5, c = cid & 31;
    const int t0 = c * CT;

    const unsigned short* qB = Qb + ((size_t)bh * T_ + t0) * 64;
    const unsigned short* kB = Kb + ((size_t)bh * T_ + t0) * 64;
    const unsigned short* vB = Vt + (size_t)bh * 64 * T_ + t0;
    const unsigned short* sB = SpT + (size_t)cid * 4096;
    const unsigned short* zB = Zp + (size_t)cid * 64;

    // ---- phase 1: P^T = K . Q^T for s-rows [w*32, w*32+32) ----
    bf16x8 ka[2][2];
#pragma unroll
    for (int si = 0; si < 2; ++si)
#pragma unroll
        for (int kt = 0; kt < 2; ++kt)
            ka[si][kt] = *(const bf16x8*)&kB[(w * 32 + si * 16 + lo) * 64 + kt * 32 + hi * 8];

    f32x4 pacc[2][8] = {};
#pragma unroll
    for (int ti = 0; ti < 8; ++ti) {
        if (ti >= 2 * w) {              // wave-uniform triangular skip
#pragma unroll
            for (int kt = 0; kt < 2; ++kt) {
                bf16x8 qf = *(const bf16x8*)&qB[(ti * 16 + lo) * 64 + kt * 32 + hi * 8];
                pacc[0][ti] = __builtin_amdgcn_mfma_f32_16x16x32_bf16(
                    ka[0][kt], qf, pacc[0][ti], 0, 0, 0);
                if (ti >= 2 * w + 1)
                    pacc[1][ti] = __builtin_amdgcn_mfma_f32_16x16x32_bf16(
                        ka[1][kt], qf, pacc[1][ti], 0, 0, 0);
            }
        }
    }
    // mask + write Pt[t][s] (bf16, XOR swizzle byte^=(t&7)<<4)
#pragma unroll
    for (int ti = 0; ti < 8; ++ti) {
        if (ti >= 2 * w) {
            const int t = ti * 16 + lo;
#pragma unroll
            for (int si = 0; si < 2; ++si) {
                const int s0 = w * 32 + si * 16 + hi * 4;
                ushort4 pk;
                unsigned short* pe = (unsigned short*)&pk;
#pragma unroll
                for (int j = 0; j < 4; ++j)
                    pe[j] = (s0 + j <= t) ? f2bf(pacc[si][ti][j]) : (unsigned short)0;
                *(ushort4*)((char*)lds + t * 256 + ((s0 * 2) ^ ((t & 7) << 4))) = pk;
            }
        }
    }
    __syncthreads();

    // ---- phase 2: numext[t][e'] over e' in 0..79 ----
    const bf16x8 ones8 = {0x3F80, 0x3F80, 0x3F80, 0x3F80,
                          0x3F80, 0x3F80, 0x3F80, 0x3F80};
    f32x4 acc[2][5] = {};
#pragma unroll
    for (int kt = 0; kt < 6; ++kt) {
        const int skt = kt - 2;
        if (kt < 2 || skt <= w) {       // wave-uniform triangular skip
            bf16x8 bfr[5];
            if (kt < 2) {               // d-tiles: Q . [Sp | z]
#pragma unroll
                for (int et = 0; et < 4; ++et)
                    bfr[et] = *(const bf16x8*)&sB[(et * 16 + lo) * 64 + kt * 32 + hi * 8];
                bfr[4] = *(const bf16x8*)&zB[kt * 32 + hi * 8];  // every row = z
            } else {                    // s-tiles: P . [V | 1]
#pragma unroll
                for (int et = 0; et < 4; ++et)
                    bfr[et] = *(const bf16x8*)&vB[(size_t)(et * 16 + lo) * T_ + skt * 32 + hi * 8];
                bfr[4] = ones8;
            }
#pragma unroll
            for (int m = 0; m < 2; ++m) {
                const int t = w * 32 + m * 16 + lo;
                bf16x8 af;
                if (kt < 2)
                    af = *(const bf16x8*)&qB[t * 64 + kt * 32 + hi * 8];
                else
                    af = *(const bf16x8*)((char*)lds + t * 256 +
                         (((skt * 32 + hi * 8) * 2) ^ ((t & 7) << 4)));
#pragma unroll
                for (int et = 0; et < 5; ++et)
                    acc[m][et] = __builtin_amdgcn_mfma_f32_16x16x32_bf16(
                        af, bfr[et], acc[m][et], 0, 0, 0);
            }
        }
    }

    __syncthreads();    // all Pt reads done; reuse lds for out staging
    // out-stage: o[t][e] bf16, stride 72 (144B rows, 16B-aligned)
#pragma unroll
    for (int m = 0; m < 2; ++m) {
#pragma unroll
        for (int j = 0; j < 4; ++j) {
            const int t = w * 32 + m * 16 + hi * 4 + j;
            const float rden = 1.f / (acc[m][4][j] + EPSC);   // cols 64..79 = den
#pragma unroll
            for (int et = 0; et < 4; ++et) {
                const int e = et * 16 + lo;
                *(unsigned short*)((char*)lds + t * 144 + e * 2) =
                    f2bf(acc[m][et][j] * rden);
            }
        }
    }
    __syncthreads();
    // coalesced global write: 16B per thread x4
    const int b = bh >> 4, h = bh & 15;
#pragma unroll
    for (int r = 0; r < 4; ++r) {
        const int vid = tid + r * 256;          // 0..1023
        const int t = vid >> 3, eg = vid & 7;
        uint4 val = *(const uint4*)((const char*)lds + t * 144 + eg * 16);
        *(uint4*)&att[(size_t)(b * T_ + t0 + t) * E_ + h * 64 + eg * 8] = val;
    }
}

// ---------------------------------------------------------------------------
extern "C" void kernel_launch(void* const* d_in, const int* in_sizes, int n_in,
                              void* d_out, int out_size, void* d_ws, size_t ws_size,
                              hipStream_t stream)
{
    const float* x  = (const float*)d_in[0];
    const float* wq = (const float*)d_in[1];
    const float* bq = (const float*)d_in[2];
    const float* wk = (const float*)d_in[3];
    const float* bk = (const float*)d_in[4];
    const float* wv = (const float*)d_in[5];
    const float* bv = (const float*)d_in[6];
    const float* wo = (const float*)d_in[7];
    const float* bo = (const float*)d_in[8];
    float* out = (float*)d_out;

    // workspace layout (MB): qb 0-16 | kb 16-32 | ktb 32-48 | vtb 48-64 |
    //   xb 64-80 (aliased by attb) | Sl 80-88 | Zl 88-88.125 | wT 88.125-96.125
    char* ws = (char*)d_ws;
    unsigned short* qb  = (unsigned short*)(ws);
    unsigned short* kb  = (unsigned short*)(ws + (size_t)16 * 1024 * 1024);
    unsigned short* ktb = (unsigned short*)(ws + (size_t)32 * 1024 * 1024);
    unsigned short* vtb = (unsigned short*)(ws + (size_t)48 * 1024 * 1024);
    unsigned short* xb  = (unsigned short*)(ws + (size_t)64 * 1024 * 1024);
    unsigned short* attb = xb;   // xb dead after V GEMM
    unsigned short* Sl  = (unsigned short*)(ws + (size_t)80 * 1024 * 1024);
    unsigned short* Zl  = (unsigned short*)(ws + (size_t)88 * 1024 * 1024);
    unsigned short* wqT = (unsigned short*)(ws + (size_t)88 * 1024 * 1024 + 128 * 1024);
    unsigned short* wkT = wqT + (size_t)KDIM * NDIM;
    unsigned short* wvT = wkT + (size_t)KDIM * NDIM;
    unsigned short* woT = wvT + (size_t)KDIM * NDIM;

    conv_bf16<<<M_ * KDIM / (256 * 8), 256, 0, stream>>>(x, xb);
    transpose_w4<<<dim3(16, 16, 4), 256, 0, stream>>>(wq, wk, wv, wo,
                                                      wqT, wkT, wvT, woT);

    const dim3 gg(NDIM / 128, M_ / 128);
    gemm_bf16<1><<<gg, 256, 0, stream>>>(xb, wqT, bq, qb, nullptr, nullptr);
    gemm_bf16<3><<<gg, 256, 0, stream>>>(xb, wkT, bk, kb, ktb, nullptr);
    gemm_bf16<0><<<gg, 256, 0, stream>>>(xb, wvT, bv, nullptr, vtb, nullptr);

    chunk_sums_mfma<<<B_ * H_ * NC, 256, 0, stream>>>(ktb, vtb, Sl, Zl);
    chunk_scan_bf<<<dim3(8, B_ * H_), 256, 0, stream>>>(Sl, Zl);
    chunk_attn_mfma<<<B_ * H_ * NC, 256, 0, stream>>>(qb, kb, vtb, Sl, Zl, attb);

    gemm_bf16<2><<<gg, 256, 0, stream>>>(attb, woT, bo, nullptr, nullptr, out);
}

// Round 4
// 171.100 us; speedup vs baseline: 6.8472x; 1.1096x over previous
//
#include <hip/hip_runtime.h>
#include <hip/hip_bf16.h>
#include <cstdint>
#include <cstddef>

// Problem constants
#define B_   2
#define T_   4096
#define E_   1024
#define H_   16
#define D_   64
#define M_   (B_ * T_)       // 8192 rows
#define KDIM 1024
#define NDIM 1024
#define EPSC 1e-6f
#define CT   128             // chunk length
#define NC   (T_ / CT)       // 32 chunks per (b,h)

typedef __attribute__((ext_vector_type(8))) short bf16x8;
typedef __attribute__((ext_vector_type(4))) float f32x4;

// ---------- small helpers ----------
__device__ __forceinline__ float bf2f(uint32_t u) {
    union { uint32_t u; float f; } x; x.u = u << 16; return x.f;
}
__device__ __forceinline__ unsigned short f2bf(float f) {
    union { float f; uint32_t u; } x; x.f = f;
    uint32_t r = x.u + 0x7fffu + ((x.u >> 16) & 1u);   // RNE
    return (unsigned short)(r >> 16);
}
__device__ __forceinline__ void gload16(const void* g, void* l) {
    __builtin_amdgcn_global_load_lds(
        (const __attribute__((address_space(1))) void*)g,
        (__attribute__((address_space(3))) void*)l, 16, 0, 0);
}

// ---------------------------------------------------------------------------
// fp32 -> bf16 bulk convert (x). Each thread: 8 floats.
// ---------------------------------------------------------------------------
__global__ __launch_bounds__(256) void conv_bf16(
    const float* __restrict__ in, unsigned short* __restrict__ out)
{
    const int i = blockIdx.x * 256 + threadIdx.x;
    const float4* p = (const float4*)in;
    float4 a = p[i * 2], b = p[i * 2 + 1];
    ushort4 o0 = make_ushort4(f2bf(a.x), f2bf(a.y), f2bf(a.z), f2bf(a.w));
    ushort4 o1 = make_ushort4(f2bf(b.x), f2bf(b.y), f2bf(b.z), f2bf(b.w));
    *(ushort4*)&out[(size_t)i * 8] = o0;
    *(ushort4*)&out[(size_t)i * 8 + 4] = o1;
}

// ---------------------------------------------------------------------------
// Transpose + convert the four 1024x1024 fp32 weights to bf16 [N][K].
// o0..o2 are written CONTIGUOUSLY (one [3072][1024] matrix for fused QKV).
// ---------------------------------------------------------------------------
__global__ __launch_bounds__(256) void transpose_w4(
    const float* __restrict__ w0, const float* __restrict__ w1,
    const float* __restrict__ w2, const float* __restrict__ w3,
    unsigned short* __restrict__ o0, unsigned short* __restrict__ o1,
    unsigned short* __restrict__ o2, unsigned short* __restrict__ o3)
{
    const float* src; unsigned short* dst;
    switch (blockIdx.z) {
        case 0: src = w0; dst = o0; break;
        case 1: src = w1; dst = o1; break;
        case 2: src = w2; dst = o2; break;
        default: src = w3; dst = o3; break;
    }
    __shared__ float tile[64][65];
    const int t = threadIdx.x, tx = t & 63, ty = t >> 6;
    const int r0 = blockIdx.y * 64, c0 = blockIdx.x * 64;
#pragma unroll
    for (int i = 0; i < 16; ++i)
        tile[ty + i * 4][tx] = src[(size_t)(r0 + ty + i * 4) * KDIM + c0 + tx];
    __syncthreads();
#pragma unroll
    for (int i = 0; i < 16; ++i)
        dst[(size_t)(c0 + ty + i * 4) * KDIM + r0 + tx] = f2bf(tile[tx][ty + i * 4]);
}

// ---------------------------------------------------------------------------
// Fused QKV GEMM, pipelined: BM=BN=256, BK=32, 8 waves (2Mx4N), 3-deep LDS
// pipeline (96 KB), counted vmcnt(4) at tile boundary, raw s_barrier,
// st_16x32 XOR swizzle via pre-swizzled global source, XCD-chunked swizzle.
//   C[8192][3072] = xb . Wt^T + bias; cols 0-1023 -> Q (elu+1, rowmajor),
//   1024-2047 -> K (elu+1, rowmajor + transposed), 2048-3071 -> V (transposed).
// ---------------------------------------------------------------------------
__global__ __launch_bounds__(512, 2) void gemm_qkv3(
    const unsigned short* __restrict__ A,    // [8192][1024] bf16
    const unsigned short* __restrict__ Wt,   // [3072][1024] bf16 (N-major)
    const float* __restrict__ bq, const float* __restrict__ bk,
    const float* __restrict__ bv,
    unsigned short* __restrict__ qb,  unsigned short* __restrict__ kb,
    unsigned short* __restrict__ ktb, unsigned short* __restrict__ vtb)
{
    __shared__ char lds[98304];   // A bufs: 3 x 16KB @0, B bufs: 3 x 16KB @48K

    const int tid  = threadIdx.x;
    const int lane = tid & 63;
    const int w    = tid >> 6;       // 0..7
    const int wm   = w >> 2;         // 0..1 (row half, 128)
    const int wn   = w & 3;          // 0..3 (col quarter, 64)
    const int lo   = lane & 15, hi = lane >> 4;

    // XCD-chunked bijective swizzle: 384 blocks, 384 % 8 == 0
    const int orig = blockIdx.x;
    const int swz  = (orig & 7) * 48 + (orig >> 3);
    const int bx = swz % 12;         // 12 col tiles of 256
    const int by = swz / 12;         // 32 row tiles of 256
    const int row0 = by * 256;
    const int col0 = bx * 256;

    // Pre-swizzled staging sources. Slot s = j*512+tid, dest byte X = s*16.
    // Logical Y = X ^ (((X>>9)&1)<<5); row=(Y>>10)*16+((Y>>6)&15); k=(Y&63)>>1.
    const unsigned short* pa0; const unsigned short* pa1;
    const unsigned short* pb0; const unsigned short* pb1;
    {
        int X, Y, r, ko;
        X = tid * 16;           Y = X ^ (((X >> 9) & 1) << 5);
        r = ((Y >> 10) << 4) + ((Y >> 6) & 15);  ko = (Y & 63) >> 1;
        pa0 = A  + (size_t)(row0 + r) * KDIM + ko;
        pb0 = Wt + (size_t)(col0 + r) * KDIM + ko;
        X = (512 + tid) * 16;   Y = X ^ (((X >> 9) & 1) << 5);
        r = ((Y >> 10) << 4) + ((Y >> 6) & 15);  ko = (Y & 63) >> 1;
        pa1 = A  + (size_t)(row0 + r) * KDIM + ko;
        pb1 = Wt + (size_t)(col0 + r) * KDIM + ko;
    }
    const int woff = w * 1024;       // wave's linear dest chunk (bytes)

    // ds_read fragment offset (bytes, within a buffer), swizzled
    const int rdb = lo * 64 + hi * 16;
    const int fragoff = rdb ^ (((rdb >> 9) & 1) << 5);

#define LDSA(b) (lds + (b) * 16384)
#define LDSB(b) (lds + 49152 + (b) * 16384)
#define STAGE_A(t, b) { gload16(pa0 + (t) * 32, LDSA(b) + woff); \
                        gload16(pa1 + (t) * 32, LDSA(b) + 8192 + woff); }
#define STAGE_B(t, b) { gload16(pb0 + (t) * 32, LDSB(b) + woff); \
                        gload16(pb1 + (t) * 32, LDSB(b) + 8192 + woff); }

    f32x4 acc[8][4] = {};
    const int NT = KDIM / 32;        // 32 K-tiles

    // prologue: tiles 0,1 in flight; wait tile 0 (4 newest outstanding = tile 1)
    STAGE_A(0, 0); STAGE_B(0, 0);
    STAGE_A(1, 1); STAGE_B(1, 1);
    asm volatile("s_waitcnt vmcnt(4)" ::: "memory");
    __builtin_amdgcn_s_barrier();

    for (int t = 0; t < NT; ++t) {
        const int cb = t % 3;
        const char* bufA = LDSA(cb);
        const char* bufB = LDSB(cb);
        const int nb = (t + 2) % 3;
        const bool more = (t + 2 < NT);

        // ---- phase 1: B frags + A rows 0-3, MFMA m0-3 ----
        if (more) STAGE_A(t + 2, nb);
        bf16x8 bfr[4], af[4];
#pragma unroll
        for (int n = 0; n < 4; ++n)
            bfr[n] = *(const bf16x8*)(bufB + (wn * 4 + n) * 1024 + fragoff);
#pragma unroll
        for (int m = 0; m < 4; ++m)
            af[m] = *(const bf16x8*)(bufA + (wm * 8 + m) * 1024 + fragoff);
        asm volatile("s_waitcnt lgkmcnt(0)" ::: "memory");
        __builtin_amdgcn_sched_barrier(0);
        __builtin_amdgcn_s_setprio(1);
#pragma unroll
        for (int m = 0; m < 4; ++m)
#pragma unroll
            for (int n = 0; n < 4; ++n)
                acc[m][n] = __builtin_amdgcn_mfma_f32_16x16x32_bf16(
                    af[m], bfr[n], acc[m][n], 0, 0, 0);
        __builtin_amdgcn_s_setprio(0);

        // ---- phase 2: A rows 4-7, MFMA m4-7 ----
        if (more) STAGE_B(t + 2, nb);
        bf16x8 af2[4];
#pragma unroll
        for (int m = 0; m < 4; ++m)
            af2[m] = *(const bf16x8*)(bufA + (wm * 8 + 4 + m) * 1024 + fragoff);
        asm volatile("s_waitcnt lgkmcnt(0)" ::: "memory");
        __builtin_amdgcn_sched_barrier(0);
        __builtin_amdgcn_s_setprio(1);
#pragma unroll
        for (int m = 0; m < 4; ++m)
#pragma unroll
            for (int n = 0; n < 4; ++n)
                acc[4 + m][n] = __builtin_amdgcn_mfma_f32_16x16x32_bf16(
                    af2[m], bfr[n], acc[4 + m][n], 0, 0, 0);
        __builtin_amdgcn_s_setprio(0);

        // ---- tile boundary: counted wait (t+1 landed), raw barrier ----
        if (more) asm volatile("s_waitcnt vmcnt(4)" ::: "memory");
        else      asm volatile("s_waitcnt vmcnt(0)" ::: "memory");
        __builtin_amdgcn_s_barrier();
    }
#undef STAGE_A
#undef STAGE_B
#undef LDSA
#undef LDSB

    // ---- epilogue: C/D mapping col=lane&15, row=(lane>>4)*4+j ----
    const int matid = bx >> 2;                 // 0=Q 1=K 2=V
    const int lcol0 = (bx & 3) * 256;
    const float* bias = (matid == 0) ? bq : (matid == 1) ? bk : bv;
    const int fcol = lane & 15, frow4 = (lane >> 4) * 4;
#pragma unroll
    for (int m = 0; m < 8; ++m) {
#pragma unroll
        for (int n = 0; n < 4; ++n) {
            const int lcol = lcol0 + wn * 64 + n * 16 + fcol;
            const float bval = bias[lcol];
            const int rbase = row0 + wm * 128 + m * 16 + frow4;
            const int h = lcol >> 6, d = lcol & 63;
            const int bb = rbase >> 12;
            const int tt = rbase & (T_ - 1);
            float vv[4];
#pragma unroll
            for (int j = 0; j < 4; ++j) {
                float v = acc[m][n][j] + bval;
                if (matid <= 1) v = (v > 0.f) ? (v + 1.f) : __expf(v);
                vv[j] = v;
            }
            if (matid == 0) {
#pragma unroll
                for (int j = 0; j < 4; ++j)
                    qb[((((size_t)bb * H_ + h) * T_) + tt + j) * D_ + d] = f2bf(vv[j]);
            } else if (matid == 1) {
#pragma unroll
                for (int j = 0; j < 4; ++j)
                    kb[((((size_t)bb * H_ + h) * T_) + tt + j) * D_ + d] = f2bf(vv[j]);
                ushort4 tp = make_ushort4(f2bf(vv[0]), f2bf(vv[1]),
                                          f2bf(vv[2]), f2bf(vv[3]));
                *(ushort4*)&ktb[(((size_t)bb * H_ + h) * D_ + d) * T_ + tt] = tp;
            } else {
                ushort4 tp = make_ushort4(f2bf(vv[0]), f2bf(vv[1]),
                                          f2bf(vv[2]), f2bf(vv[3]));
                *(ushort4*)&vtb[(((size_t)bb * H_ + h) * D_ + d) * T_ + tt] = tp;
            }
        }
    }
}

// ---------------------------------------------------------------------------
// Output projection GEMM (m97 structure, proven) + XCD swizzle. f32 out.
// ---------------------------------------------------------------------------
__global__ __launch_bounds__(256) void gemm_out(
    const unsigned short* __restrict__ A,   // attb [8192][1024] bf16
    const unsigned short* __restrict__ Bt,  // woT [1024][1024] bf16
    const float* __restrict__ bias, float* __restrict__ outf)
{
    __shared__ unsigned short As[128 * 32];
    __shared__ unsigned short Bs[128 * 32];

    const int tid  = threadIdx.x;
    const int lane = tid & 63;
    const int wave = tid >> 6;
    const int wr = wave >> 1, wc = wave & 1;
    const int orig = blockIdx.x;                 // 512 blocks
    const int swz  = (orig & 7) * 64 + (orig >> 3);
    const int bx = swz & 7, by = swz >> 3;
    const int row0 = by * 128;
    const int col0 = bx * 128;

    f32x4 acc[4][4] = {};

    const unsigned short* Ag = A  + (size_t)(row0 + (tid >> 2)) * KDIM + (tid & 3) * 8;
    const unsigned short* Bg = Bt + (size_t)(col0 + (tid >> 2)) * KDIM + (tid & 3) * 8;
    unsigned short* AsW = As + wave * 512;
    unsigned short* BsW = Bs + wave * 512;

    const int fr = lane & 15;
    const int fk = (lane >> 4) * 8;

    for (int k0 = 0; k0 < KDIM; k0 += 32) {
        gload16(Ag + k0,              AsW);
        gload16(Ag + 64 * KDIM + k0,  AsW + 2048);
        gload16(Bg + k0,              BsW);
        gload16(Bg + 64 * KDIM + k0,  BsW + 2048);
        __syncthreads();

        bf16x8 af[4], bfr[4];
#pragma unroll
        for (int m = 0; m < 4; ++m)
            af[m] = *(const bf16x8*)&As[(wr * 64 + m * 16 + fr) * 32 + fk];
#pragma unroll
        for (int n = 0; n < 4; ++n)
            bfr[n] = *(const bf16x8*)&Bs[(wc * 64 + n * 16 + fr) * 32 + fk];
#pragma unroll
        for (int m = 0; m < 4; ++m)
#pragma unroll
            for (int n = 0; n < 4; ++n)
                acc[m][n] = __builtin_amdgcn_mfma_f32_16x16x32_bf16(
                    af[m], bfr[n], acc[m][n], 0, 0, 0);
        __syncthreads();
    }

    const int fcol = lane & 15;
    const int frow = (lane >> 4) * 4;
#pragma unroll
    for (int m = 0; m < 4; ++m) {
#pragma unroll
        for (int n = 0; n < 4; ++n) {
            const int col = col0 + wc * 64 + n * 16 + fcol;
            const float bval = bias[col];
            const int rbase = row0 + wr * 64 + m * 16 + frow;
#pragma unroll
            for (int j = 0; j < 4; ++j)
                outf[(size_t)(rbase + j) * NDIM + col] = acc[m][n][j] + bval;
        }
    }
}

// ---------------------------------------------------------------------------
// Phase A (MFMA): per-chunk S_local = K^T V (+ z via ones-cols), bf16 out.
// ---------------------------------------------------------------------------
__global__ __launch_bounds__(256) void chunk_sums_mfma(
    const unsigned short* __restrict__ Kt,  // [BH][64][T]
    const unsigned short* __restrict__ Vt,  // [BH][64][T]
    unsigned short* __restrict__ Sl,        // [BH*NC][64*64]
    unsigned short* __restrict__ Zl)        // [BH*NC][64]
{
    const int tid = threadIdx.x, lane = tid & 63, w = tid >> 6;
    const int lo = lane & 15, hi = lane >> 4;
    const int cid = blockIdx.x, bh = cid >> 5, c = cid & 31, t0 = c * CT;
    const unsigned short* kT = Kt + (size_t)bh * 64 * T_ + t0;
    const unsigned short* vT = Vt + (size_t)bh * 64 * T_ + t0;

    const bf16x8 ones8 = {0x3F80, 0x3F80, 0x3F80, 0x3F80,
                          0x3F80, 0x3F80, 0x3F80, 0x3F80};
    f32x4 acc[5] = {};
#pragma unroll
    for (int kt = 0; kt < 4; ++kt) {
        bf16x8 af = *(const bf16x8*)&kT[(size_t)(w * 16 + lo) * T_ + kt * 32 + hi * 8];
        bf16x8 bfr[5];
#pragma unroll
        for (int et = 0; et < 4; ++et)
            bfr[et] = *(const bf16x8*)&vT[(size_t)(et * 16 + lo) * T_ + kt * 32 + hi * 8];
        bfr[4] = ones8;
#pragma unroll
        for (int et = 0; et < 5; ++et)
            acc[et] = __builtin_amdgcn_mfma_f32_16x16x32_bf16(af, bfr[et], acc[et], 0, 0, 0);
    }
    unsigned short* sO = Sl + (size_t)cid * 4096;
    const int d0 = w * 16 + hi * 4;
#pragma unroll
    for (int et = 0; et < 4; ++et) {
        const int e = et * 16 + lo;
        ushort4 pk = make_ushort4(f2bf(acc[et][0]), f2bf(acc[et][1]),
                                  f2bf(acc[et][2]), f2bf(acc[et][3]));
        *(ushort4*)&sO[e * 64 + d0] = pk;
    }
    if (lo == 0) {
        ushort4 pk = make_ushort4(f2bf(acc[4][0]), f2bf(acc[4][1]),
                                  f2bf(acc[4][2]), f2bf(acc[4][3]));
        *(ushort4*)&Zl[(size_t)cid * 64 + d0] = pk;
    }
}

// ---------------------------------------------------------------------------
// Phase B: in-place exclusive prefix over chunks, bf16, f32 accumulation.
// ---------------------------------------------------------------------------
__global__ __launch_bounds__(256) void chunk_scan_bf(
    unsigned short* __restrict__ S, unsigned short* __restrict__ Z)
{
    const int bh = blockIdx.y;
    const int f0 = blockIdx.x * 512 + threadIdx.x * 2;
    float a0 = 0.f, a1 = 0.f;
    unsigned short* base = S + (size_t)bh * NC * 4096 + f0;
    for (int c = 0; c < NC; ++c) {
        uint32_t* p = (uint32_t*)(base + (size_t)c * 4096);
        uint32_t v = *p;
        float c0 = bf2f(v & 0xffffu), c1 = bf2f(v >> 16);
        *p = (uint32_t)f2bf(a0) | ((uint32_t)f2bf(a1) << 16);
        a0 += c0; a1 += c1;
    }
    if (blockIdx.x == 0 && threadIdx.x < 32) {
        float b0 = 0.f, b1 = 0.f;
        unsigned short* zb = Z + (size_t)bh * NC * 64 + threadIdx.x * 2;
        for (int c = 0; c < NC; ++c) {
            uint32_t* p = (uint32_t*)(zb + (size_t)c * 64);
            uint32_t v = *p;
            float c0 = bf2f(v & 0xffffu), c1 = bf2f(v >> 16);
            *p = (uint32_t)f2bf(b0) | ((uint32_t)f2bf(b1) << 16);
            b0 += c0; b1 += c1;
        }
    }
}

// ---------------------------------------------------------------------------
// Phase C (MFMA): P^T = K.Q^T (masked), numext = Q.[Sp|z] + P.[V|1].
// ---------------------------------------------------------------------------
__global__ __launch_bounds__(256) void chunk_attn_mfma(
    const unsigned short* __restrict__ Qb,  // [BH][T][64]
    const unsigned short* __restrict__ Kb,  // [BH][T][64]
    const unsigned short* __restrict__ Vt,  // [BH][64][T]
    const unsigned short* __restrict__ SpT, // [BH*NC][64*64] prefix [e][d]
    const unsigned short* __restrict__ Zp,  // [BH*NC][64] prefix
    unsigned short* __restrict__ att)       // [M][1024]
{
    __shared__ unsigned short lds[128 * 128];

    const int tid = threadIdx.x;
    const int lane = tid & 63;
    const int w = tid >> 6;
    const int lo = lane & 15, hi = lane >> 4;
    const int cid = blockIdx.x;
    const int bh = cid >> 5, c = cid & 31;
    const int t0 = c * CT;

    const unsigned short* qB = Qb + ((size_t)bh * T_ + t0) * 64;
    const unsigned short* kB = Kb + ((size_t)bh * T_ + t0) * 64;
    const unsigned short* vB = Vt + (size_t)bh * 64 * T_ + t0;
    const unsigned short* sB = SpT + (size_t)cid * 4096;
    const unsigned short* zB = Zp + (size_t)cid * 64;

    bf16x8 ka[2][2];
#pragma unroll
    for (int si = 0; si < 2; ++si)
#pragma unroll
        for (int kt = 0; kt < 2; ++kt)
            ka[si][kt] = *(const bf16x8*)&kB[(w * 32 + si * 16 + lo) * 64 + kt * 32 + hi * 8];

    f32x4 pacc[2][8] = {};
#pragma unroll
    for (int ti = 0; ti < 8; ++ti) {
        if (ti >= 2 * w) {
#pragma unroll
            for (int kt = 0; kt < 2; ++kt) {
                bf16x8 qf = *(const bf16x8*)&qB[(ti * 16 + lo) * 64 + kt * 32 + hi * 8];
                pacc[0][ti] = __builtin_amdgcn_mfma_f32_16x16x32_bf16(
                    ka[0][kt], qf, pacc[0][ti], 0, 0, 0);
                if (ti >= 2 * w + 1)
                    pacc[1][ti] = __builtin_amdgcn_mfma_f32_16x16x32_bf16(
                        ka[1][kt], qf, pacc[1][ti], 0, 0, 0);
            }
        }
    }
#pragma unroll
    for (int ti = 0; ti < 8; ++ti) {
        if (ti >= 2 * w) {
            const int t = ti * 16 + lo;
#pragma unroll
            for (int si = 0; si < 2; ++si) {
                const int s0 = w * 32 + si * 16 + hi * 4;
                ushort4 pk;
                unsigned short* pe = (unsigned short*)&pk;
#pragma unroll
                for (int j = 0; j < 4; ++j)
                    pe[j] = (s0 + j <= t) ? f2bf(pacc[si][ti][j]) : (unsigned short)0;
                *(ushort4*)((char*)lds + t * 256 + ((s0 * 2) ^ ((t & 7) << 4))) = pk;
            }
        }
    }
    __syncthreads();

    const bf16x8 ones8 = {0x3F80, 0x3F80, 0x3F80, 0x3F80,
                          0x3F80, 0x3F80, 0x3F80, 0x3F80};
    f32x4 acc[2][5] = {};
#pragma unroll
    for (int kt = 0; kt < 6; ++kt) {
        const int skt = kt - 2;
        if (kt < 2 || skt <= w) {
            bf16x8 bfr[5];
            if (kt < 2) {
#pragma unroll
                for (int et = 0; et < 4; ++et)
                    bfr[et] = *(const bf16x8*)&sB[(et * 16 + lo) * 64 + kt * 32 + hi * 8];
                bfr[4] = *(const bf16x8*)&zB[kt * 32 + hi * 8];
            } else {
#pragma unroll
                for (int et = 0; et < 4; ++et)
                    bfr[et] = *(const bf16x8*)&vB[(size_t)(et * 16 + lo) * T_ + skt * 32 + hi * 8];
                bfr[4] = ones8;
            }
#pragma unroll
            for (int m = 0; m < 2; ++m) {
                const int t = w * 32 + m * 16 + lo;
                bf16x8 af;
                if (kt < 2)
                    af = *(const bf16x8*)&qB[t * 64 + kt * 32 + hi * 8];
                else
                    af = *(const bf16x8*)((char*)lds + t * 256 +
                         (((skt * 32 + hi * 8) * 2) ^ ((t & 7) << 4)));
#pragma unroll
                for (int et = 0; et < 5; ++et)
                    acc[m][et] = __builtin_amdgcn_mfma_f32_16x16x32_bf16(
                        af, bfr[et], acc[m][et], 0, 0, 0);
            }
        }
    }

    __syncthreads();
#pragma unroll
    for (int m = 0; m < 2; ++m) {
#pragma unroll
        for (int j = 0; j < 4; ++j) {
            const int t = w * 32 + m * 16 + hi * 4 + j;
            const float rden = 1.f / (acc[m][4][j] + EPSC);
#pragma unroll
            for (int et = 0; et < 4; ++et) {
                const int e = et * 16 + lo;
                *(unsigned short*)((char*)lds + t * 144 + e * 2) =
                    f2bf(acc[m][et][j] * rden);
            }
        }
    }
    __syncthreads();
    const int b = bh >> 4, h = bh & 15;
#pragma unroll
    for (int r = 0; r < 4; ++r) {
        const int vid = tid + r * 256;
        const int t = vid >> 3, eg = vid & 7;
        uint4 val = *(const uint4*)((const char*)lds + t * 144 + eg * 16);
        *(uint4*)&att[(size_t)(b * T_ + t0 + t) * E_ + h * 64 + eg * 8] = val;
    }
}

// ---------------------------------------------------------------------------
extern "C" void kernel_launch(void* const* d_in, const int* in_sizes, int n_in,
                              void* d_out, int out_size, void* d_ws, size_t ws_size,
                              hipStream_t stream)
{
    const float* x  = (const float*)d_in[0];
    const float* wq = (const float*)d_in[1];
    const float* bq = (const float*)d_in[2];
    const float* wk = (const float*)d_in[3];
    const float* bk = (const float*)d_in[4];
    const float* wv = (const float*)d_in[5];
    const float* bv = (const float*)d_in[6];
    const float* wo = (const float*)d_in[7];
    const float* bo = (const float*)d_in[8];
    float* out = (float*)d_out;

    // workspace layout (MB): qb 0-16 | kb 16-32 | ktb 32-48 | vtb 48-64 |
    //   xb 64-80 (aliased by attb) | Sl 80-88 | Zl 88-88.125 | wT 88.125-96.125
    char* ws = (char*)d_ws;
    unsigned short* qb  = (unsigned short*)(ws);
    unsigned short* kb  = (unsigned short*)(ws + (size_t)16 * 1024 * 1024);
    unsigned short* ktb = (unsigned short*)(ws + (size_t)32 * 1024 * 1024);
    unsigned short* vtb = (unsigned short*)(ws + (size_t)48 * 1024 * 1024);
    unsigned short* xb  = (unsigned short*)(ws + (size_t)64 * 1024 * 1024);
    unsigned short* attb = xb;   // xb dead after QKV GEMM
    unsigned short* Sl  = (unsigned short*)(ws + (size_t)80 * 1024 * 1024);
    unsigned short* Zl  = (unsigned short*)(ws + (size_t)88 * 1024 * 1024);
    unsigned short* wqT = (unsigned short*)(ws + (size_t)88 * 1024 * 1024 + 128 * 1024);
    unsigned short* wkT = wqT + (size_t)KDIM * NDIM;   // contiguous [3072][1024]
    unsigned short* wvT = wkT + (size_t)KDIM * NDIM;
    unsigned short* woT = wvT + (size_t)KDIM * NDIM;

    conv_bf16<<<M_ * KDIM / (256 * 8), 256, 0, stream>>>(x, xb);
    transpose_w4<<<dim3(16, 16, 4), 256, 0, stream>>>(wq, wk, wv, wo,
                                                      wqT, wkT, wvT, woT);

    gemm_qkv3<<<384, 512, 0, stream>>>(xb, wqT, bq, bk, bv, qb, kb, ktb, vtb);

    chunk_sums_mfma<<<B_ * H_ * NC, 256, 0, stream>>>(ktb, vtb, Sl, Zl);
    chunk_scan_bf<<<dim3(8, B_ * H_), 256, 0, stream>>>(Sl, Zl);
    chunk_attn_mfma<<<B_ * H_ * NC, 256, 0, stream>>>(qb, kb, vtb, Sl, Zl, attb);

    gemm_out<<<512, 256, 0, stream>>>(attb, woT, bo, out);
}

// Round 5
// 165.926 us; speedup vs baseline: 7.0607x; 1.0312x over previous
//
#include <hip/hip_runtime.h>
#include <hip/hip_bf16.h>
#include <cstdint>
#include <cstddef>

// Problem constants
#define B_   2
#define T_   4096
#define E_   1024
#define H_   16
#define D_   64
#define M_   (B_ * T_)       // 8192 rows
#define KDIM 1024
#define NDIM 1024
#define EPSC 1e-6f
#define CT   128             // chunk length
#define NC   (T_ / CT)       // 32 chunks per (b,h)

typedef __attribute__((ext_vector_type(8))) short bf16x8;
typedef __attribute__((ext_vector_type(4))) float f32x4;

// ---------- small helpers ----------
__device__ __forceinline__ float bf2f(uint32_t u) {
    union { uint32_t u; float f; } x; x.u = u << 16; return x.f;
}
__device__ __forceinline__ unsigned short f2bf(float f) {
    union { float f; uint32_t u; } x; x.f = f;
    uint32_t r = x.u + 0x7fffu + ((x.u >> 16) & 1u);   // RNE
    return (unsigned short)(r >> 16);
}
__device__ __forceinline__ void gload16(const void* g, void* l) {
    __builtin_amdgcn_global_load_lds(
        (const __attribute__((address_space(1))) void*)g,
        (__attribute__((address_space(3))) void*)l, 16, 0, 0);
}

// ---------------------------------------------------------------------------
// fp32 -> bf16 bulk convert (x). Each thread: 8 floats.
// ---------------------------------------------------------------------------
__global__ __launch_bounds__(256) void conv_bf16(
    const float* __restrict__ in, unsigned short* __restrict__ out)
{
    const int i = blockIdx.x * 256 + threadIdx.x;
    const float4* p = (const float4*)in;
    float4 a = p[i * 2], b = p[i * 2 + 1];
    ushort4 o0 = make_ushort4(f2bf(a.x), f2bf(a.y), f2bf(a.z), f2bf(a.w));
    ushort4 o1 = make_ushort4(f2bf(b.x), f2bf(b.y), f2bf(b.z), f2bf(b.w));
    *(ushort4*)&out[(size_t)i * 8] = o0;
    *(ushort4*)&out[(size_t)i * 8 + 4] = o1;
}

// ---------------------------------------------------------------------------
// Transpose + convert the four 1024x1024 fp32 weights to bf16 [N][K].
// o0..o2 written contiguously (one [3072][1024] matrix for fused QKV).
// ---------------------------------------------------------------------------
__global__ __launch_bounds__(256) void transpose_w4(
    const float* __restrict__ w0, const float* __restrict__ w1,
    const float* __restrict__ w2, const float* __restrict__ w3,
    unsigned short* __restrict__ o0, unsigned short* __restrict__ o1,
    unsigned short* __restrict__ o2, unsigned short* __restrict__ o3)
{
    const float* src; unsigned short* dst;
    switch (blockIdx.z) {
        case 0: src = w0; dst = o0; break;
        case 1: src = w1; dst = o1; break;
        case 2: src = w2; dst = o2; break;
        default: src = w3; dst = o3; break;
    }
    __shared__ float tile[64][65];
    const int t = threadIdx.x, tx = t & 63, ty = t >> 6;
    const int r0 = blockIdx.y * 64, c0 = blockIdx.x * 64;
#pragma unroll
    for (int i = 0; i < 16; ++i)
        tile[ty + i * 4][tx] = src[(size_t)(r0 + ty + i * 4) * KDIM + c0 + tx];
    __syncthreads();
#pragma unroll
    for (int i = 0; i < 16; ++i)
        dst[(size_t)(c0 + ty + i * 4) * KDIM + r0 + tx] = f2bf(tile[tx][ty + i * 4]);
}

// ---------------------------------------------------------------------------
// Fused QKV GEMM, 8-phase schedule (T2+T3+T4+T5):
//   BM=BN=256, BK=64, 8 waves (2Mx4N), per-wave 128x64 output.
//   2-buffer LDS (128 KB), 4 sub-phases per K-tile, 1 half-tile prefetch per
//   phase, counted vmcnt(4) at tile boundary, 2 barriers per K-tile,
//   3-bit XOR swizzle X^=((X>>7)&7)<<4 (even 8-lanes/slot -> conflict-free),
//   linear LDS dest via pre-swizzled global source, setprio around MFMA.
// Staging plan (tile t, buf c=t&1, o=c^1):
//   ph0: stage B0(t+1)->bufB[o]; read bfr[4][2]+af[0..1][2]; lgkm0; MFMA m0-1
//   ph1: stage B1(t+1)->bufB[o]; read af[2..7][2]; lgkm0; BARRIER; MFMA m2-3
//   ph2: stage A0(t+2)->bufA[c] (all A-reads of bufA[c] done); MFMA m4-5
//   ph3: stage A1(t+2)->bufA[c]; MFMA m6-7; vmcnt(4); BARRIER
// ---------------------------------------------------------------------------
__global__ __launch_bounds__(512, 2) void gemm_qkv8(
    const unsigned short* __restrict__ A,    // [8192][1024] bf16
    const unsigned short* __restrict__ Wt,   // [3072][1024] bf16 (N-major)
    const float* __restrict__ bq, const float* __restrict__ bk,
    const float* __restrict__ bv,
    unsigned short* __restrict__ qb,  unsigned short* __restrict__ kb,
    unsigned short* __restrict__ ktb, unsigned short* __restrict__ vtb)
{
    __shared__ char lds[131072];   // A: 2x32KB @0, B: 2x32KB @64KB

    const int tid  = threadIdx.x;
    const int lane = tid & 63;
    const int w    = tid >> 6;       // 0..7
    const int wm   = w >> 2;         // 0..1 (row half, 128 rows)
    const int wn   = w & 3;          // 0..3 (col quarter, 64 cols)
    const int lo   = lane & 15, hi = lane >> 4;

    // XCD-chunked bijective swizzle: 384 blocks, 384 % 8 == 0
    const int orig = blockIdx.x;
    const int swz  = (orig & 7) * 48 + (orig >> 3);
    const int bx = swz % 12;         // 12 col tiles of 256
    const int by = swz / 12;         // 32 row tiles of 256
    const int row0 = by * 256;
    const int col0 = bx * 256;

    // staging source precompute: dest slot s=j*512+tid in a 16KB half-tile,
    // dest byte X=s*16 (linear); logical Y = X ^ (((X>>7)&7)<<4);
    // row = Y>>7 (0..127 within half), k-elem = (Y&127)>>1 (mult of 8).
    int sr0, sk0, sr1, sk1;
    { int X = tid * 16;         int Y = X ^ (((X >> 7) & 7) << 4);
      sr0 = Y >> 7; sk0 = (Y & 127) >> 1; }
    { int X = (512 + tid) * 16; int Y = X ^ (((X >> 7) & 7) << 4);
      sr1 = Y >> 7; sk1 = (Y & 127) >> 1; }
    const unsigned short* sA0 = A  + (size_t)(row0 + sr0) * KDIM + sk0;
    const unsigned short* sA1 = A  + (size_t)(row0 + sr1) * KDIM + sk1;
    const unsigned short* sB0 = Wt + (size_t)(col0 + sr0) * KDIM + sk0;
    const unsigned short* sB1 = Wt + (size_t)(col0 + sr1) * KDIM + sk1;

#define BUFA(p) (lds + (p) * 32768)
#define BUFB(p) (lds + 65536 + (p) * 32768)
#define STGA(t, h) { char* d_ = BUFA((t) & 1) + (h) * 16384 + w * 1024;      \
        gload16(sA0 + (size_t)(h) * 128 * KDIM + (t) * 64, d_);              \
        gload16(sA1 + (size_t)(h) * 128 * KDIM + (t) * 64, d_ + 8192); }
#define STGB(t, h) { char* d_ = BUFB((t) & 1) + (h) * 16384 + w * 1024;      \
        gload16(sB0 + (size_t)(h) * 128 * KDIM + (t) * 64, d_);              \
        gload16(sB1 + (size_t)(h) * 128 * KDIM + (t) * 64, d_ + 8192); }

    // ds_read frag offsets: logical col-byte (kk*64 + hi*16) XOR ((row&7)<<4);
    // row&7 == lane&7 for all frag rows (row = base16*n + lo).
    const int koff0 = (hi * 16)      ^ ((lane & 7) << 4);
    const int koff1 = (64 + hi * 16) ^ ((lane & 7) << 4);

    f32x4  acc[8][4] = {};
    bf16x8 af[8][2], bfr[4][2];

#define MFMA_PAIR(mb) {                                                       \
    _Pragma("unroll") for (int kk = 0; kk < 2; ++kk)                          \
    _Pragma("unroll") for (int n = 0; n < 4; ++n) {                           \
        acc[mb][n]     = __builtin_amdgcn_mfma_f32_16x16x32_bf16(             \
            af[mb][kk],     bfr[n][kk], acc[mb][n], 0, 0, 0);                 \
        acc[mb + 1][n] = __builtin_amdgcn_mfma_f32_16x16x32_bf16(             \
            af[mb + 1][kk], bfr[n][kk], acc[mb + 1][n], 0, 0, 0);             \
    } }

    // prologue: A(0),B(0),A(1) in flight; wait A(0),B(0) landed (keep 4 newest)
    STGA(0, 0); STGA(0, 1); STGB(0, 0); STGB(0, 1);
    STGA(1, 0); STGA(1, 1);
    asm volatile("s_waitcnt vmcnt(4)" ::: "memory");
    __builtin_amdgcn_s_barrier();

    const int NT = KDIM / 64;        // 16 K-tiles
#pragma unroll 2
    for (int t = 0; t < NT; ++t) {
        const char* bA = BUFA(t & 1);
        const char* bB = BUFB(t & 1);

        // ---- phase 0 ----
        if (t + 1 < NT) STGB(t + 1, 0);
#pragma unroll
        for (int n = 0; n < 4; ++n) {
            const char* p = bB + (wn * 64 + n * 16 + lo) * 128;
            bfr[n][0] = *(const bf16x8*)(p + koff0);
            bfr[n][1] = *(const bf16x8*)(p + koff1);
        }
#pragma unroll
        for (int m = 0; m < 2; ++m) {
            const char* p = bA + (wm * 128 + m * 16 + lo) * 128;
            af[m][0] = *(const bf16x8*)(p + koff0);
            af[m][1] = *(const bf16x8*)(p + koff1);
        }
        asm volatile("s_waitcnt lgkmcnt(0)" ::: "memory");
        __builtin_amdgcn_sched_barrier(0);
        __builtin_amdgcn_s_setprio(1);
        MFMA_PAIR(0);
        __builtin_amdgcn_s_setprio(0);
        __builtin_amdgcn_sched_barrier(0);

        // ---- phase 1 ----
        if (t + 1 < NT) STGB(t + 1, 1);
#pragma unroll
        for (int m = 2; m < 8; ++m) {
            const char* p = bA + (wm * 128 + m * 16 + lo) * 128;
            af[m][0] = *(const bf16x8*)(p + koff0);
            af[m][1] = *(const bf16x8*)(p + koff1);
        }
        asm volatile("s_waitcnt lgkmcnt(0)" ::: "memory");
        __builtin_amdgcn_sched_barrier(0);
        __builtin_amdgcn_s_barrier();            // all reads of bufA[c] done
        __builtin_amdgcn_s_setprio(1);
        MFMA_PAIR(2);
        __builtin_amdgcn_s_setprio(0);
        __builtin_amdgcn_sched_barrier(0);

        // ---- phase 2: A-halves of bufA[c] free -> stage A(t+2) ----
        if (t + 2 < NT) STGA(t + 2, 0);
        __builtin_amdgcn_s_setprio(1);
        MFMA_PAIR(4);
        __builtin_amdgcn_s_setprio(0);
        __builtin_amdgcn_sched_barrier(0);

        // ---- phase 3 ----
        if (t + 2 < NT) STGA(t + 2, 1);
        __builtin_amdgcn_s_setprio(1);
        MFMA_PAIR(6);
        __builtin_amdgcn_s_setprio(0);
        if (t + 2 < NT) asm volatile("s_waitcnt vmcnt(4)" ::: "memory");
        else            asm volatile("s_waitcnt vmcnt(0)" ::: "memory");
        __builtin_amdgcn_s_barrier();
    }
#undef STGA
#undef STGB
#undef BUFA
#undef BUFB
#undef MFMA_PAIR

    // ---- epilogue: C/D mapping col=lane&15, row=(lane>>4)*4+j ----
    const int matid = bx >> 2;                 // 0=Q 1=K 2=V
    const int lcol0 = (bx & 3) * 256;
    const float* bias = (matid == 0) ? bq : (matid == 1) ? bk : bv;
    const int frow4 = hi * 4;
#pragma unroll
    for (int m = 0; m < 8; ++m) {
#pragma unroll
        for (int n = 0; n < 4; ++n) {
            const int lcol = lcol0 + wn * 64 + n * 16 + lo;
            const float bval = bias[lcol];
            const int rbase = row0 + wm * 128 + m * 16 + frow4;
            const int h = lcol >> 6, d = lcol & 63;
            const int bb = rbase >> 12;
            const int tt = rbase & (T_ - 1);
            float vv[4];
#pragma unroll
            for (int j = 0; j < 4; ++j) {
                float v = acc[m][n][j] + bval;
                if (matid <= 1) v = (v > 0.f) ? (v + 1.f) : __expf(v);
                vv[j] = v;
            }
            if (matid == 0) {
#pragma unroll
                for (int j = 0; j < 4; ++j)
                    qb[((((size_t)bb * H_ + h) * T_) + tt + j) * D_ + d] = f2bf(vv[j]);
            } else if (matid == 1) {
#pragma unroll
                for (int j = 0; j < 4; ++j)
                    kb[((((size_t)bb * H_ + h) * T_) + tt + j) * D_ + d] = f2bf(vv[j]);
                ushort4 tp = make_ushort4(f2bf(vv[0]), f2bf(vv[1]),
                                          f2bf(vv[2]), f2bf(vv[3]));
                *(ushort4*)&ktb[(((size_t)bb * H_ + h) * D_ + d) * T_ + tt] = tp;
            } else {
                ushort4 tp = make_ushort4(f2bf(vv[0]), f2bf(vv[1]),
                                          f2bf(vv[2]), f2bf(vv[3]));
                *(ushort4*)&vtb[(((size_t)bb * H_ + h) * D_ + d) * T_ + tt] = tp;
            }
        }
    }
}

// ---------------------------------------------------------------------------
// Output projection GEMM (m97 structure, proven) + XCD swizzle. f32 out.
// ---------------------------------------------------------------------------
__global__ __launch_bounds__(256) void gemm_out(
    const unsigned short* __restrict__ A,   // attb [8192][1024] bf16
    const unsigned short* __restrict__ Bt,  // woT [1024][1024] bf16
    const float* __restrict__ bias, float* __restrict__ outf)
{
    __shared__ unsigned short As[128 * 32];
    __shared__ unsigned short Bs[128 * 32];

    const int tid  = threadIdx.x;
    const int lane = tid & 63;
    const int wave = tid >> 6;
    const int wr = wave >> 1, wc = wave & 1;
    const int orig = blockIdx.x;                 // 512 blocks
    const int swz  = (orig & 7) * 64 + (orig >> 3);
    const int bx = swz & 7, by = swz >> 3;
    const int row0 = by * 128;
    const int col0 = bx * 128;

    f32x4 acc[4][4] = {};

    const unsigned short* Ag = A  + (size_t)(row0 + (tid >> 2)) * KDIM + (tid & 3) * 8;
    const unsigned short* Bg = Bt + (size_t)(col0 + (tid >> 2)) * KDIM + (tid & 3) * 8;
    unsigned short* AsW = As + wave * 512;
    unsigned short* BsW = Bs + wave * 512;

    const int fr = lane & 15;
    const int fk = (lane >> 4) * 8;

    for (int k0 = 0; k0 < KDIM; k0 += 32) {
        gload16(Ag + k0,              AsW);
        gload16(Ag + 64 * KDIM + k0,  AsW + 2048);
        gload16(Bg + k0,              BsW);
        gload16(Bg + 64 * KDIM + k0,  BsW + 2048);
        __syncthreads();

        bf16x8 af[4], bfr[4];
#pragma unroll
        for (int m = 0; m < 4; ++m)
            af[m] = *(const bf16x8*)&As[(wr * 64 + m * 16 + fr) * 32 + fk];
#pragma unroll
        for (int n = 0; n < 4; ++n)
            bfr[n] = *(const bf16x8*)&Bs[(wc * 64 + n * 16 + fr) * 32 + fk];
#pragma unroll
        for (int m = 0; m < 4; ++m)
#pragma unroll
            for (int n = 0; n < 4; ++n)
                acc[m][n] = __builtin_amdgcn_mfma_f32_16x16x32_bf16(
                    af[m], bfr[n], acc[m][n], 0, 0, 0);
        __syncthreads();
    }

    const int fcol = lane & 15;
    const int frow = (lane >> 4) * 4;
#pragma unroll
    for (int m = 0; m < 4; ++m) {
#pragma unroll
        for (int n = 0; n < 4; ++n) {
            const int col = col0 + wc * 64 + n * 16 + fcol;
            const float bval = bias[col];
            const int rbase = row0 + wr * 64 + m * 16 + frow;
#pragma unroll
            for (int j = 0; j < 4; ++j)
                outf[(size_t)(rbase + j) * NDIM + col] = acc[m][n][j] + bval;
        }
    }
}

// ---------------------------------------------------------------------------
// Phase A (MFMA): per-chunk S_local = K^T V (+ z via ones-cols), bf16 out.
// ---------------------------------------------------------------------------
__global__ __launch_bounds__(256) void chunk_sums_mfma(
    const unsigned short* __restrict__ Kt,  // [BH][64][T]
    const unsigned short* __restrict__ Vt,  // [BH][64][T]
    unsigned short* __restrict__ Sl,        // [BH*NC][64*64]
    unsigned short* __restrict__ Zl)        // [BH*NC][64]
{
    const int tid = threadIdx.x, lane = tid & 63, w = tid >> 6;
    const int lo = lane & 15, hi = lane >> 4;
    const int cid = blockIdx.x, bh = cid >> 5, c = cid & 31, t0 = c * CT;
    const unsigned short* kT = Kt + (size_t)bh * 64 * T_ + t0;
    const unsigned short* vT = Vt + (size_t)bh * 64 * T_ + t0;

    const bf16x8 ones8 = {0x3F80, 0x3F80, 0x3F80, 0x3F80,
                          0x3F80, 0x3F80, 0x3F80, 0x3F80};
    f32x4 acc[5] = {};
#pragma unroll
    for (int kt = 0; kt < 4; ++kt) {
        bf16x8 af = *(const bf16x8*)&kT[(size_t)(w * 16 + lo) * T_ + kt * 32 + hi * 8];
        bf16x8 bfr[5];
#pragma unroll
        for (int et = 0; et < 4; ++et)
            bfr[et] = *(const bf16x8*)&vT[(size_t)(et * 16 + lo) * T_ + kt * 32 + hi * 8];
        bfr[4] = ones8;
#pragma unroll
        for (int et = 0; et < 5; ++et)
            acc[et] = __builtin_amdgcn_mfma_f32_16x16x32_bf16(af, bfr[et], acc[et], 0, 0, 0);
    }
    unsigned short* sO = Sl + (size_t)cid * 4096;
    const int d0 = w * 16 + hi * 4;
#pragma unroll
    for (int et = 0; et < 4; ++et) {
        const int e = et * 16 + lo;
        ushort4 pk = make_ushort4(f2bf(acc[et][0]), f2bf(acc[et][1]),
                                  f2bf(acc[et][2]), f2bf(acc[et][3]));
        *(ushort4*)&sO[e * 64 + d0] = pk;
    }
    if (lo == 0) {
        ushort4 pk = make_ushort4(f2bf(acc[4][0]), f2bf(acc[4][1]),
                                  f2bf(acc[4][2]), f2bf(acc[4][3]));
        *(ushort4*)&Zl[(size_t)cid * 64 + d0] = pk;
    }
}

// ---------------------------------------------------------------------------
// Phase B: in-place exclusive prefix over chunks, bf16, f32 accumulation.
// ---------------------------------------------------------------------------
__global__ __launch_bounds__(256) void chunk_scan_bf(
    unsigned short* __restrict__ S, unsigned short* __restrict__ Z)
{
    const int bh = blockIdx.y;
    const int f0 = blockIdx.x * 512 + threadIdx.x * 2;
    float a0 = 0.f, a1 = 0.f;
    unsigned short* base = S + (size_t)bh * NC * 4096 + f0;
    for (int c = 0; c < NC; ++c) {
        uint32_t* p = (uint32_t*)(base + (size_t)c * 4096);
        uint32_t v = *p;
        float c0 = bf2f(v & 0xffffu), c1 = bf2f(v >> 16);
        *p = (uint32_t)f2bf(a0) | ((uint32_t)f2bf(a1) << 16);
        a0 += c0; a1 += c1;
    }
    if (blockIdx.x == 0 && threadIdx.x < 32) {
        float b0 = 0.f, b1 = 0.f;
        unsigned short* zb = Z + (size_t)bh * NC * 64 + threadIdx.x * 2;
        for (int c = 0; c < NC; ++c) {
            uint32_t* p = (uint32_t*)(zb + (size_t)c * 64);
            uint32_t v = *p;
            float c0 = bf2f(v & 0xffffu), c1 = bf2f(v >> 16);
            *p = (uint32_t)f2bf(b0) | ((uint32_t)f2bf(b1) << 16);
            b0 += c0; b1 += c1;
        }
    }
}

// ---------------------------------------------------------------------------
// Phase C (MFMA): P^T = K.Q^T (masked), numext = Q.[Sp|z] + P.[V|1].
// ---------------------------------------------------------------------------
__global__ __launch_bounds__(256) void chunk_attn_mfma(
    const unsigned short* __restrict__ Qb,  // [BH][T][64]
    const unsigned short* __restrict__ Kb,  // [BH][T][64]
    const unsigned short* __restrict__ Vt,  // [BH][64][T]
    const unsigned short* __restrict__ SpT, // [BH*NC][64*64] prefix [e][d]
    const unsigned short* __restrict__ Zp,  // [BH*NC][64] prefix
    unsigned short* __restrict__ att)       // [M][1024]
{
    __shared__ unsigned short lds[128 * 128];

    const int tid = threadIdx.x;
    const int lane = tid & 63;
    const int w = tid >> 6;
    const int lo = lane & 15, hi = lane >> 4;
    const int cid = blockIdx.x;
    const int bh = cid >> 5, c = cid & 31;
    const int t0 = c * CT;

    const unsigned short* qB = Qb + ((size_t)bh * T_ + t0) * 64;
    const unsigned short* kB = Kb + ((size_t)bh * T_ + t0) * 64;
    const unsigned short* vB = Vt + (size_t)bh * 64 * T_ + t0;
    const unsigned short* sB = SpT + (size_t)cid * 4096;
    const unsigned short* zB = Zp + (size_t)cid * 64;

    bf16x8 ka[2][2];
#pragma unroll
    for (int si = 0; si < 2; ++si)
#pragma unroll
        for (int kt = 0; kt < 2; ++kt)
            ka[si][kt] = *(const bf16x8*)&kB[(w * 32 + si * 16 + lo) * 64 + kt * 32 + hi * 8];

    f32x4 pacc[2][8] = {};
#pragma unroll
    for (int ti = 0; ti < 8; ++ti) {
        if (ti >= 2 * w) {
#pragma unroll
            for (int kt = 0; kt < 2; ++kt) {
                bf16x8 qf = *(const bf16x8*)&qB[(ti * 16 + lo) * 64 + kt * 32 + hi * 8];
                pacc[0][ti] = __builtin_amdgcn_mfma_f32_16x16x32_bf16(
                    ka[0][kt], qf, pacc[0][ti], 0, 0, 0);
                if (ti >= 2 * w + 1)
                    pacc[1][ti] = __builtin_amdgcn_mfma_f32_16x16x32_bf16(
                        ka[1][kt], qf, pacc[1][ti], 0, 0, 0);
            }
        }
    }
#pragma unroll
    for (int ti = 0; ti < 8; ++ti) {
        if (ti >= 2 * w) {
            const int t = ti * 16 + lo;
#pragma unroll
            for (int si = 0; si < 2; ++si) {
                const int s0 = w * 32 + si * 16 + hi * 4;
                ushort4 pk;
                unsigned short* pe = (unsigned short*)&pk;
#pragma unroll
                for (int j = 0; j < 4; ++j)
                    pe[j] = (s0 + j <= t) ? f2bf(pacc[si][ti][j]) : (unsigned short)0;
                *(ushort4*)((char*)lds + t * 256 + ((s0 * 2) ^ ((t & 7) << 4))) = pk;
            }
        }
    }
    __syncthreads();

    const bf16x8 ones8 = {0x3F80, 0x3F80, 0x3F80, 0x3F80,
                          0x3F80, 0x3F80, 0x3F80, 0x3F80};
    f32x4 acc[2][5] = {};
#pragma unroll
    for (int kt = 0; kt < 6; ++kt) {
        const int skt = kt - 2;
        if (kt < 2 || skt <= w) {
            bf16x8 bfr[5];
            if (kt < 2) {
#pragma unroll
                for (int et = 0; et < 4; ++et)
                    bfr[et] = *(const bf16x8*)&sB[(et * 16 + lo) * 64 + kt * 32 + hi * 8];
                bfr[4] = *(const bf16x8*)&zB[kt * 32 + hi * 8];
            } else {
#pragma unroll
                for (int et = 0; et < 4; ++et)
                    bfr[et] = *(const bf16x8*)&vB[(size_t)(et * 16 + lo) * T_ + skt * 32 + hi * 8];
                bfr[4] = ones8;
            }
#pragma unroll
            for (int m = 0; m < 2; ++m) {
                const int t = w * 32 + m * 16 + lo;
                bf16x8 af;
                if (kt < 2)
                    af = *(const bf16x8*)&qB[t * 64 + kt * 32 + hi * 8];
                else
                    af = *(const bf16x8*)((char*)lds + t * 256 +
                         (((skt * 32 + hi * 8) * 2) ^ ((t & 7) << 4)));
#pragma unroll
                for (int et = 0; et < 5; ++et)
                    acc[m][et] = __builtin_amdgcn_mfma_f32_16x16x32_bf16(
                        af, bfr[et], acc[m][et], 0, 0, 0);
            }
        }
    }

    __syncthreads();
#pragma unroll
    for (int m = 0; m < 2; ++m) {
#pragma unroll
        for (int j = 0; j < 4; ++j) {
            const int t = w * 32 + m * 16 + hi * 4 + j;
            const float rden = 1.f / (acc[m][4][j] + EPSC);
#pragma unroll
            for (int et = 0; et < 4; ++et) {
                const int e = et * 16 + lo;
                *(unsigned short*)((char*)lds + t * 144 + e * 2) =
                    f2bf(acc[m][et][j] * rden);
            }
        }
    }
    __syncthreads();
    const int b = bh >> 4, h = bh & 15;
#pragma unroll
    for (int r = 0; r < 4; ++r) {
        const int vid = tid + r * 256;
        const int t = vid >> 3, eg = vid & 7;
        uint4 val = *(const uint4*)((const char*)lds + t * 144 + eg * 16);
        *(uint4*)&att[(size_t)(b * T_ + t0 + t) * E_ + h * 64 + eg * 8] = val;
    }
}

// ---------------------------------------------------------------------------
extern "C" void kernel_launch(void* const* d_in, const int* in_sizes, int n_in,
                              void* d_out, int out_size, void* d_ws, size_t ws_size,
                              hipStream_t stream)
{
    const float* x  = (const float*)d_in[0];
    const float* wq = (const float*)d_in[1];
    const float* bq = (const float*)d_in[2];
    const float* wk = (const float*)d_in[3];
    const float* bk = (const float*)d_in[4];
    const float* wv = (const float*)d_in[5];
    const float* bv = (const float*)d_in[6];
    const float* wo = (const float*)d_in[7];
    const float* bo = (const float*)d_in[8];
    float* out = (float*)d_out;

    // workspace layout (MB): qb 0-16 | kb 16-32 | ktb 32-48 | vtb 48-64 |
    //   xb 64-80 (aliased by attb) | Sl 80-88 | Zl 88-88.125 | wT 88.125-96.125
    char* ws = (char*)d_ws;
    unsigned short* qb  = (unsigned short*)(ws);
    unsigned short* kb  = (unsigned short*)(ws + (size_t)16 * 1024 * 1024);
    unsigned short* ktb = (unsigned short*)(ws + (size_t)32 * 1024 * 1024);
    unsigned short* vtb = (unsigned short*)(ws + (size_t)48 * 1024 * 1024);
    unsigned short* xb  = (unsigned short*)(ws + (size_t)64 * 1024 * 1024);
    unsigned short* attb = xb;   // xb dead after QKV GEMM
    unsigned short* Sl  = (unsigned short*)(ws + (size_t)80 * 1024 * 1024);
    unsigned short* Zl  = (unsigned short*)(ws + (size_t)88 * 1024 * 1024);
    unsigned short* wqT = (unsigned short*)(ws + (size_t)88 * 1024 * 1024 + 128 * 1024);
    unsigned short* wkT = wqT + (size_t)KDIM * NDIM;   // contiguous [3072][1024]
    unsigned short* wvT = wkT + (size_t)KDIM * NDIM;
    unsigned short* woT = wvT + (size_t)KDIM * NDIM;

    conv_bf16<<<M_ * KDIM / (256 * 8), 256, 0, stream>>>(x, xb);
    transpose_w4<<<dim3(16, 16, 4), 256, 0, stream>>>(wq, wk, wv, wo,
                                                      wqT, wkT, wvT, woT);

    gemm_qkv8<<<384, 512, 0, stream>>>(xb, wqT, bq, bk, bv, qb, kb, ktb, vtb);

    chunk_sums_mfma<<<B_ * H_ * NC, 256, 0, stream>>>(ktb, vtb, Sl, Zl);
    chunk_scan_bf<<<dim3(8, B_ * H_), 256, 0, stream>>>(Sl, Zl);
    chunk_attn_mfma<<<B_ * H_ * NC, 256, 0, stream>>>(qb, kb, vtb, Sl, Zl, attb);

    gemm_out<<<512, 256, 0, stream>>>(attb, woT, bo, out);
}